// Round 9
// baseline (270.813 us; speedup 1.0000x reference)
//
#include <hip/hip_runtime.h>
#include <stdint.h>

#define N_NODES 50000
#define E_EDGES 300000
#define C_CH    256
#define H_HEADS 8
#define NB2     64       // blocks in counting sort
#define CHUNK2  4688     // edges per sort block (64*4688 >= 300000)
#define NBIN    4096     // 256 dst x 16 src-ranges
#define SRCDIV  3125     // 50000/16 -> src-range = s/3125
#define NWG_GEMM 1568    // 391*4 (K,V m-tiles) + 4 (Q)
#define NWG_LN   12436   // (50000-256)/4 ln-tail blocks
#define GOFF     2       // gemm blocks start at blockIdx 2 (0=scan, 1=SPD)

typedef unsigned short u16;
typedef unsigned int   u32;

typedef __attribute__((ext_vector_type(8))) short  v8s;   // 8 bf16 (MFMA A/B frag)
typedef __attribute__((ext_vector_type(4))) float  v4f;   // MFMA C/D frag

__device__ __forceinline__ float bf2f(u16 v) {
    union { u32 u; float f; } x; x.u = ((u32)v) << 16; return x.f;
}
__device__ __forceinline__ u16 f2bf(float f) {
    union { float f; u32 u; } x; x.f = f;
    u32 r = (x.u + 0x7FFFu + ((x.u >> 16) & 1u)) >> 16;
    return (u16)r;
}
__device__ __forceinline__ void unp2(u32 v, float& lo, float& hi) {
    union { u32 u; float f; } x;
    x.u = v << 16; lo = x.f;
    x.u = v & 0xFFFF0000u; hi = x.f;
}
// async global->LDS, 16 B/lane; LDS dest = wave-uniform base + lane*16
__device__ __forceinline__ void gl_lds16(const u16* g, u16* l) {
    __builtin_amdgcn_global_load_lds(
        (const __attribute__((address_space(1))) void*)g,
        (__attribute__((address_space(3))) void*)l, 16, 0, 0);
}
// pack 8 fp32 -> 8 bf16, single 16B LDS store (round-4 exact)
__device__ __forceinline__ void pack8(const float4 p, const float4 q, u16* dst) {
    u16 tmp[8];
    tmp[0]=f2bf(p.x); tmp[1]=f2bf(p.y); tmp[2]=f2bf(p.z); tmp[3]=f2bf(p.w);
    tmp[4]=f2bf(q.x); tmp[5]=f2bf(q.y); tmp[6]=f2bf(q.z); tmp[7]=f2bf(q.w);
    *(uint4*)dst = *(const uint4*)tmp;
}

// ---------------------------------------------------------------------------
// prep_k: blocks 0..191 convert Wk,Wv,Wq -> bf16 Wb; blocks 192..255 run the
// (dst, src-range) histogram + per-block anchor masks (no global atomics —
// scan/SPD blocks of the megakernel reduce them); blocks 256..321 zero the
// denom+outf region (replaces hipMemsetAsync).
// ---------------------------------------------------------------------------
__global__ __launch_bounds__(256) void prep_k(
    const float* __restrict__ Wk, const float* __restrict__ Wv,
    const float* __restrict__ Wq, u16* __restrict__ Wb,
    const int* __restrict__ src, const int* __restrict__ dst,
    u32* __restrict__ blockhist, u32* __restrict__ pinmask,
    u32* __restrict__ zero0)
{
    __shared__ u32 hist[NBIN];          // 16 KB
    __shared__ u32 mask[256][8];        //  8 KB
    int t = threadIdx.x, b = blockIdx.x;
    if (b < 192) {
        int m = (b < 64) ? 0 : (b < 128) ? 1 : 2;
        const float* sp = (m == 0) ? Wk : (m == 1) ? Wv : Wq;
        u16* dp = Wb + m * 65536;
        int i = (b & 63) * 1024 + t * 4;
        float4 v = *(const float4*)(sp + i);
        ushort4 o;
        o.x = f2bf(v.x); o.y = f2bf(v.y); o.z = f2bf(v.z); o.w = f2bf(v.w);
        *(ushort4*)(dp + i) = o;
        return;
    }
    if (b >= 256) {                      // zero blocks: 66 x 4096 B = 270336 B
        int z = b - 256;
        uint4 zv = make_uint4(0, 0, 0, 0);
        *(uint4*)(zero0 + z * 1024 + t * 4) = zv;
        return;
    }
    int hb = b - 192;                    // 0..63
#pragma unroll
    for (int j = 0; j < 16; j++) hist[t + j * 256] = 0;
#pragma unroll
    for (int w = 0; w < 8; w++) mask[t][w] = 0;
    __syncthreads();
    int start = hb * CHUNK2;
    int end = start + CHUNK2; if (end > E_EDGES) end = E_EDGES;
    for (int e = start + t; e < end; e += 256) {
        int d = dst[e], s = src[e];
        atomicAdd(&hist[d * 16 + s / SRCDIV], 1u);     // LDS atomic
        if (s < 256) atomicOr(&mask[d][s >> 5], 1u << (s & 31));
    }
    __syncthreads();
#pragma unroll
    for (int j = 0; j < 16; j++)
        blockhist[hb * NBIN + t + j * 256] = hist[t + j * 256];
#pragma unroll
    for (int w = 0; w < 8; w++)          // transposed: [hb][w][i], coalesced
        pinmask[hb * 2048 + w * 256 + t] = mask[t][w];
}

// ---------------------------------------------------------------------------
// Megakernel.  Block 0: scan (sums blockhist -> bin totals -> exclusive scan
// -> bin_off).  Block 1: SPD (ORs per-block masks, 3-level reachability ->
// T).  Blocks 2..1569: bf16 GEMM OUT[*,256] = bf16(x) @ W^T + bias — EXACT
// round-4/8 inner code (43.4us; rounds 5/6/7 proved every core edit at the
// 64-VGPR cliff regresses).  Dead Q-blocks removed (grid 2346 -> 1568).
// Blocks 1570..14005: LayerNorm for nodes 256..49999.  Special blocks sit at
// blockIdx 0/1 so they are scheduled first and hide under the gemm+ln span.
// ---------------------------------------------------------------------------
__global__ __launch_bounds__(256, 4) void gemm3(
    const float* __restrict__ x, const u16* __restrict__ Wb,
    const float* __restrict__ bk, const float* __restrict__ bv,
    const float* __restrict__ bq,
    u16* __restrict__ Kb, u16* __restrict__ Vb, u16* __restrict__ Qb,
    const u32* __restrict__ blockhist, u32* __restrict__ bin_off,
    const u32* __restrict__ pinmask, unsigned char* __restrict__ T,
    const float* __restrict__ gamma, const float* __restrict__ beta,
    float* __restrict__ y)
{
    __shared__ u16 smem[4][128 * 32];   // A dbuf = smem[0,1], B dbuf = smem[2,3]
    const int t = threadIdx.x;

    if (blockIdx.x == 0) {
        // ---- scan: totals from blockhist, exclusive scan -> bin_off ----
        u32* tots = (u32*)&smem[0][0];            // 16 KB
        u32* tsum = tots + NBIN;                  //  1 KB
#pragma unroll
        for (int j = 0; j < 16; j++) {
            u32 s = 0;
            for (int b2 = 0; b2 < NB2; b2++)
                s += blockhist[b2 * NBIN + j * 256 + t];
            tots[j * 256 + t] = s;
        }
        __syncthreads();
        u32 loc[16]; u32 a = 0;
#pragma unroll
        for (int j = 0; j < 16; j++) { loc[j] = tots[t * 16 + j]; a += loc[j]; }
        tsum[t] = a;
        __syncthreads();
        for (int off = 1; off < 256; off <<= 1) {
            u32 add = (t >= off) ? tsum[t - off] : 0u;
            __syncthreads();
            tsum[t] += add;
            __syncthreads();
        }
        u32 base = tsum[t] - a;
#pragma unroll
        for (int j = 0; j < 16; j++) { bin_off[t * 16 + j] = base; base += loc[j]; }
        if (t == 255) bin_off[NBIN] = base;
        return;
    }
    if (blockIdx.x == 1) {
        // ---- SPD: OR per-block masks, 3-level reachability -> T ----
        u32* b32 = (u32*)&smem[0][0];
        u32 (*F1)[8] = (u32(*)[8])(b32);
        u32 (*F2)[8] = (u32(*)[8])(b32 + 2048);
        u32 (*F3)[8] = (u32(*)[8])(b32 + 4096);
        int i = t;
#pragma unroll
        for (int w = 0; w < 8; w++) {
            u32 m = 0;
            for (int b2 = 0; b2 < NB2; b2++)
                m |= pinmask[b2 * 2048 + w * 256 + i];
            F1[i][w] = m; F2[i][w] = 0; F3[i][w] = 0;
        }
        __syncthreads();
        for (int w = 0; w < 8; w++) {
            u32 m = F1[i][w];
            while (m) {
                int b = __ffs(m) - 1; m &= m - 1;
                int s = w * 32 + b;
#pragma unroll
                for (int j = 0; j < 8; j++) F2[i][j] |= F1[s][j];
            }
        }
        __syncthreads();
        for (int w = 0; w < 8; w++) {
            u32 m = F1[i][w];
            while (m) {
                int b = __ffs(m) - 1; m &= m - 1;
                int s = w * 32 + b;
#pragma unroll
                for (int j = 0; j < 8; j++) F3[i][j] |= F2[s][j];
            }
        }
        __syncthreads();
        for (int w = 0; w < 8; w++) {
            u32 f1 = F1[i][w], f2 = F2[i][w], f3 = F3[i][w];
#pragma unroll
            for (int g = 0; g < 8; g++) {
                u32 word = 0;
#pragma unroll
                for (int b = 0; b < 4; b++) {
                    int bit = g * 4 + b;
                    u32 k = ((f1 >> bit) & 1u) ? 1u : ((f2 >> bit) & 1u) ? 2u
                           : ((f3 >> bit) & 1u) ? 3u : 4u;
                    word |= k << (8 * b);
                }
                *(u32*)(T + i * 256 + w * 32 + g * 4) = word;
            }
        }
        return;
    }
    if (blockIdx.x >= GOFF + NWG_GEMM) {
        // ---- LayerNorm tail: nodes 256..49999 (no agg contribution) ----
        int n = (blockIdx.x - (GOFF + NWG_GEMM)) * 4 + (t >> 6) + 256;
        int lane = t & 63;
        int ch = lane * 4;
        float4 xv = *(const float4*)(x + (size_t)n * 256 + ch);
        float h0 = xv.x, h1 = xv.y, h2 = xv.z, h3 = xv.w;
        float s = h0 + h1 + h2 + h3;
#pragma unroll
        for (int off = 1; off < 64; off <<= 1) s += __shfl_xor(s, off);
        float mu = s * (1.0f / 256.0f);
        float d0 = h0 - mu, d1 = h1 - mu, d2 = h2 - mu, d3 = h3 - mu;
        float qq = d0 * d0 + d1 * d1 + d2 * d2 + d3 * d3;
#pragma unroll
        for (int off = 1; off < 64; off <<= 1) qq += __shfl_xor(qq, off);
        float rstd = rsqrtf(qq * (1.0f / 256.0f) + 1e-5f);
        float4 gv = *(const float4*)(gamma + ch);
        float4 bv = *(const float4*)(beta + ch);
        float4 o;
        o.x = d0 * rstd * gv.x + bv.x;
        o.y = d1 * rstd * gv.y + bv.y;
        o.z = d2 * rstd * gv.z + bv.z;
        o.w = d3 * rstd * gv.w + bv.w;
        *(float4*)(y + (size_t)n * 256 + ch) = o;
        return;
    }

    // ---- GEMM (round-4 exact inner code; new compact grid) ----
    // bijective XCD-chunked swizzle (nwg=1568 % 8 == 0), m-tile-major: the
    // 4 (mat,nh) K/V blocks of an m-tile share one XCD L2.
    int gid = blockIdx.x - GOFF;
    int xcd = gid & 7, pos = gid >> 3;
    int wgid = xcd * (NWG_GEMM >> 3) + pos;      // 196 per XCD
    int mt, mat, nh;
    if (wgid < 1564) { mt = wgid >> 2; int j = wgid & 3; mat = j >> 1; nh = j & 1; }
    else             { int qi = wgid - 1564; mt = qi >> 1; mat = 2; nh = qi & 1; }
    const int m0 = mt * 128;
    const int M = (mat == 2) ? 256 : N_NODES;
    const u16* W = Wb + mat * 65536;
    const float* bias = (mat == 0) ? bk : (mat == 1) ? bv : bq;
    u16* OUT = (mat == 0) ? Kb : (mat == 1) ? Vb : Qb;
    const int n0 = nh * 128;

    const int lane = t & 63, w = t >> 6;
    const int quad = lane >> 4, l15 = lane & 15;
    const int mq = w & 1, nq = w >> 1;

    v4f acc[16];
#pragma unroll
    for (int i = 0; i < 16; i++) acc[i] = (v4f)(0.0f);

    const int lrow = lane >> 2;               // 0..15
    const int cg   = (lane & 3) * 8;          // fp32 col-group offset
    int rA0 = m0 + w * 32 + lrow; if (rA0 > 49999) rA0 = 49999;
    int rA1 = rA0 + 16;           if (rA1 > 49999) rA1 = 49999;
    const float* gA0 = x + (size_t)rA0 * 256 + cg;
    const float* gA1 = x + (size_t)rA1 * 256 + cg;
    const u16* gB = W + (size_t)(n0 + w * 32 + lrow) * 256 + (lane & 3) * 8;

    u16* ldsA = &smem[0][(w * 32 + lrow) * 32 + (lane & 3) * 8];

    float4 a00, a01, a10, a11;
#define LOADA(kt) do {                                   \
    a00 = *(const float4*)(gA0 + (kt) * 32);             \
    a01 = *(const float4*)(gA0 + (kt) * 32 + 4);         \
    a10 = *(const float4*)(gA1 + (kt) * 32);             \
    a11 = *(const float4*)(gA1 + (kt) * 32 + 4);         \
} while (0)
#define WRITEA(bi) do {                                  \
    pack8(a00, a01, ldsA + (bi) * 4096);                 \
    pack8(a10, a11, ldsA + (bi) * 4096 + 16 * 32);       \
} while (0)
#define STAGEB(bi, koff) do {                                             \
    gl_lds16(gB + (koff),            &smem[2 + (bi)][(w * 32) * 32]);     \
    gl_lds16(gB + 16 * 256 + (koff), &smem[2 + (bi)][(w * 32 + 16) * 32]);\
} while (0)

    LOADA(0);
    STAGEB(0, 0);
    WRITEA(0);
    __syncthreads();                          // drain prologue (vm + lgkm)
    for (int kt = 0; kt < 8; kt++) {
        const int cur = kt & 1;
        if (kt < 7) { LOADA(kt + 1); STAGEB(cur ^ 1, (kt + 1) * 32); }
        v8s a[4], b[4];
#pragma unroll
        for (int f = 0; f < 4; f++)
            a[f] = *(const v8s*)(&smem[cur][(mq * 64 + f * 16 + l15) * 32 + quad * 8]);
#pragma unroll
        for (int f = 0; f < 4; f++)
            b[f] = *(const v8s*)(&smem[2 + cur][(nq * 64 + f * 16 + l15) * 32 + quad * 8]);
#pragma unroll
        for (int fm = 0; fm < 4; fm++)
#pragma unroll
            for (int fn = 0; fn < 4; fn++)
                acc[fm * 4 + fn] = __builtin_amdgcn_mfma_f32_16x16x32_bf16(
                    a[fm], b[fn], acc[fm * 4 + fn], 0, 0, 0);
        if (kt < 7) WRITEA(cur ^ 1);          // fp32 loads landed under MFMA
        __syncthreads();                      // drains vm (B) + lgkm (A writes)
    }
#undef LOADA
#undef WRITEA
#undef STAGEB

    // Epilogue: stage C+bias into LDS (32 KB = all 4 buffers), coalesced
    // uint4 stores (full 64 B lines -> no write amplification).
    u16* S = &smem[0][0];
#pragma unroll
    for (int fn = 0; fn < 4; fn++) {
        int n = nq * 64 + fn * 16 + l15;
        float bi = bias[n0 + n];
#pragma unroll
        for (int fm = 0; fm < 4; fm++) {
#pragma unroll
            for (int r2 = 0; r2 < 4; r2++) {
                int row = mq * 64 + fm * 16 + quad * 4 + r2;
                S[row * 128 + n] = f2bf(acc[fm * 4 + fn][r2] + bi);
            }
        }
    }
    __syncthreads();
#pragma unroll
    for (int i = 0; i < 8; i++) {
        int c = i * 256 + t;
        int row = c >> 4;
        int m = m0 + row;
        if (m < M)
            *(uint4*)(OUT + (size_t)m * 256 + n0 + (c & 15) * 8) =
                *(const uint4*)(S + c * 8);
    }
}

// ---------------------------------------------------------------------------
// Scatter: SRC VALUES into (dst, src-range) buckets.  Each block computes
// its own per-block base (bin_off + prefix of blockhist rows < b) — replaces
// the separate base_k launch; blockhist is L2/L3-resident (1 MB).
// ---------------------------------------------------------------------------
__global__ __launch_bounds__(256) void scatter2_k(
    const int* __restrict__ src, const int* __restrict__ dst,
    const u32* __restrict__ blockhist, const u32* __restrict__ bin_off,
    u32* __restrict__ ssrc)
{
    __shared__ u32 cur[NBIN];
    int t = threadIdx.x, b = blockIdx.x;
    u32 c[16];
#pragma unroll
    for (int j = 0; j < 16; j++) c[j] = bin_off[j * 256 + t];
    for (int bp = 0; bp < b; bp++)
#pragma unroll
        for (int j = 0; j < 16; j++)
            c[j] += blockhist[bp * NBIN + j * 256 + t];
#pragma unroll
    for (int j = 0; j < 16; j++) cur[j * 256 + t] = c[j];
    __syncthreads();
    int start = b * CHUNK2;
    int end = start + CHUNK2; if (end > E_EDGES) end = E_EDGES;
    for (int e = start + t; e < end; e += 256) {
        int s = src[e];
        int bin = dst[e] * 16 + s / SRCDIV;
        u32 pos = atomicAdd(&cur[bin], 1u);   // LDS atomic
        ssrc[pos] = (u32)s;
    }
}

// ---------------------------------------------------------------------------
// Fused scores+aggregate.  blockIdx = d*16 + src-range p -> each block's K/V
// gather stays inside a 3.2 MB src window; blockIdx%8 == p%8 pins a window
// pair per XCD L2.  2-deep pipeline: src 2 iters ahead, K/V rows 1 ahead.
// ---------------------------------------------------------------------------
__global__ __launch_bounds__(256) void agg_k(
    const u32* __restrict__ ssrc, const u32* __restrict__ bin_off,
    const u16* __restrict__ Qb, const u16* __restrict__ Kb,
    const u16* __restrict__ Vb, const unsigned char* __restrict__ T,
    const float* __restrict__ spd_w, float* __restrict__ out,
    float* __restrict__ denom)
{
    __shared__ float red[4 * 256];
    __shared__ float dred[4 * 8];
    int bid = blockIdx.x;
    int d = bid >> 4;
    int t = threadIdx.x, lane = t & 63, wave = t >> 6;
    int half = lane >> 5, sl = lane & 31;
    int h = sl >> 2;                        // head = (sl*8)>>5
    u32 start = bin_off[bid], end = bin_off[bid + 1];

    uint4 qv = *(const uint4*)(Qb + (size_t)d * 256 + sl * 8);
    float q0,q1,q2,q3,q4,q5,q6,q7;
    unp2(qv.x,q0,q1); unp2(qv.y,q2,q3); unp2(qv.z,q4,q5); unp2(qv.w,q6,q7);
    float sw4 = spd_w[4 * 8 + h];           // spd=4 bias (src>=256, ~98.5%)

    float a0=0.f,a1=0.f,a2=0.f,a3=0.f,a4=0.f,a5=0.f,a6=0.f,a7=0.f,dsum=0.f;

    u32 i = start + (u32)(wave * 2 + half);  // 8 slots, stride 8
    int s_c = 0, s_n = 0;
    uint4 kv_c = make_uint4(0,0,0,0), vv_c = kv_c;
    if (i < end) {
        s_c = (int)ssrc[i];
        kv_c = *(const uint4*)(Kb + (size_t)s_c * 256 + sl * 8);
        vv_c = *(const uint4*)(Vb + (size_t)s_c * 256 + sl * 8);
        if (i + 8 < end) s_n = (int)ssrc[i + 8];
    }
    while (i < end) {
        u32 inx = i + 8;
        uint4 kv_n = kv_c, vv_n = vv_c;
        if (inx < end) {                    // issue next row loads (addr ready)
            kv_n = *(const uint4*)(Kb + (size_t)s_n * 256 + sl * 8);
            vv_n = *(const uint4*)(Vb + (size_t)s_n * 256 + sl * 8);
        }
        int s_nn = (inx + 8 < end) ? (int)ssrc[inx + 8] : 0;
        float k0,k1,k2,k3,k4,k5,k6,k7, v0,v1,v2,v3,v4,v5,v6,v7;
        unp2(kv_c.x,k0,k1); unp2(kv_c.y,k2,k3); unp2(kv_c.z,k4,k5); unp2(kv_c.w,k6,k7);
        unp2(vv_c.x,v0,v1); unp2(vv_c.y,v2,v3); unp2(vv_c.z,v4,v5); unp2(vv_c.w,v6,v7);
        float p = q0*k0+q1*k1+q2*k2+q3*k3+q4*k4+q5*k5+q6*k6+q7*k7;
        p += __shfl_xor(p, 1);
        p += __shfl_xor(p, 2);              // head dot over 4 lanes x 8 ch
        float bias = (s_c < 256) ? spd_w[(int)T[s_c * 256 + d] * 8 + h] : sw4;
        float wgt = __expf(p * 0.17677669529663689f + bias);
        a0 += wgt*v0; a1 += wgt*v1; a2 += wgt*v2; a3 += wgt*v3;
        a4 += wgt*v4; a5 += wgt*v5; a6 += wgt*v6; a7 += wgt*v7;
        if ((sl & 3) == 0) dsum += wgt;
        i = inx; s_c = s_n; s_n = s_nn; kv_c = kv_n; vv_c = vv_n;
    }
    a0 += __shfl_xor(a0,32); a1 += __shfl_xor(a1,32);
    a2 += __shfl_xor(a2,32); a3 += __shfl_xor(a3,32);
    a4 += __shfl_xor(a4,32); a5 += __shfl_xor(a5,32);
    a6 += __shfl_xor(a6,32); a7 += __shfl_xor(a7,32);
    dsum += __shfl_xor(dsum,32);
    if (half == 0) {
        *(float4*)(&red[wave * 256 + sl * 8])     = make_float4(a0,a1,a2,a3);
        *(float4*)(&red[wave * 256 + sl * 8 + 4]) = make_float4(a4,a5,a6,a7);
        if ((sl & 3) == 0) dred[wave * 8 + h] = dsum;
    }
    __syncthreads();
    float sAll = red[t] + red[256 + t] + red[512 + t] + red[768 + t];
    atomicAdd(&out[(size_t)d * 256 + t], sAll);
    if (t < 8) {
        float ds = dred[t] + dred[8 + t] + dred[16 + t] + dred[24 + t];
        atomicAdd(&denom[d * 8 + t], ds);
    }
}

// ---------------------------------------------------------------------------
// LayerNorm anchors (n < 256 only): h = out/denom + x.  Tail nodes were
// normalized inside the megakernel.  64 blocks.
// ---------------------------------------------------------------------------
__global__ __launch_bounds__(256) void ln_k(
    const float* __restrict__ x, const float* __restrict__ out,
    const float* __restrict__ denom, const float* __restrict__ gamma,
    const float* __restrict__ beta, float* __restrict__ y)
{
    int n = blockIdx.x * 4 + (threadIdx.x >> 6);
    int lane = threadIdx.x & 63;
    int ch = lane * 4;
    float4 xv = *(const float4*)(x + (size_t)n * 256 + ch);
    float h0 = xv.x, h1 = xv.y, h2 = xv.z, h3 = xv.w;
    float den = denom[n * 8 + (lane >> 3)];
    float inv = (den > 0.f) ? 1.0f / den : 0.0f;
    const float* op = out + (size_t)n * 256 + ch;
    h0 += op[0] * inv; h1 += op[1] * inv;
    h2 += op[2] * inv; h3 += op[3] * inv;
    float s = h0 + h1 + h2 + h3;
#pragma unroll
    for (int off = 1; off < 64; off <<= 1) s += __shfl_xor(s, off);
    float mu = s * (1.0f / 256.0f);
    float d0 = h0 - mu, d1 = h1 - mu, d2 = h2 - mu, d3 = h3 - mu;
    float q = d0 * d0 + d1 * d1 + d2 * d2 + d3 * d3;
#pragma unroll
    for (int off = 1; off < 64; off <<= 1) q += __shfl_xor(q, off);
    float rstd = rsqrtf(q * (1.0f / 256.0f) + 1e-5f);
    float4 gv = *(const float4*)(gamma + ch);
    float4 bv = *(const float4*)(beta + ch);
    float4 o;
    o.x = d0 * rstd * gv.x + bv.x;
    o.y = d1 * rstd * gv.y + bv.y;
    o.z = d2 * rstd * gv.z + bv.z;
    o.w = d3 * rstd * gv.w + bv.w;
    *(float4*)(y + (size_t)n * 256 + ch) = o;
}

// ---------------------------------------------------------------------------
extern "C" void kernel_launch(void* const* d_in, const int* in_sizes, int n_in,
                              void* d_out, int out_size, void* d_ws, size_t ws_size,
                              hipStream_t stream)
{
    const float* x     = (const float*)d_in[0];
    const int*   src   = (const int*)d_in[1];
    const int*   dst   = (const int*)d_in[2];
    const float* Wq    = (const float*)d_in[3];
    const float* bq    = (const float*)d_in[4];
    const float* Wk    = (const float*)d_in[5];
    const float* bk    = (const float*)d_in[6];
    const float* Wv    = (const float*)d_in[7];
    const float* bv    = (const float*)d_in[8];
    const float* spd_w = (const float*)d_in[9];
    const float* gamma = (const float*)d_in[10];
    const float* beta  = (const float*)d_in[11];
    float* y = (float*)d_out;

    char* ws = (char*)d_ws;
    // denom+outf zeroed by prep_k zero-blocks (270336 B from ws+0).
    float* denom     = (float*)(ws + 0);          //   8192 B
    float* outf      = (float*)(ws + 8192);       // 262144 B -> 270336
    u32*   bin_off   = (u32*)(ws + 270336);       //  16388 B (pad) -> 286976
    unsigned char* T = (unsigned char*)(ws + 286976); // 65536 B -> 352512
    u32*   blockhist = (u32*)(ws + 352512);       // 64*4096*4 = 1 MB -> 1401088
    u32*   pinmask   = (u32*)(ws + 1401088);      // 64*2048*4 = 512 KB -> 1925376
    u32*   ssrc      = (u32*)(ws + 1925376);      // 1.2 MB -> 3125376
    u16*   Qb        = (u16*)(ws + 3125376);      // 128 KB -> 3256448
    u16*   Kb        = (u16*)(ws + 3256448);      // 25.6 MB -> 28881024
    u16*   Vb        = (u16*)(ws + 28881024);     // 25.6 MB -> 54505600
    u16*   Wb        = (u16*)(ws + 54505600);     // 384 KB (end ~54.9 MB)

    dim3 blk(256);
    prep_k<<<dim3(322), blk, 0, stream>>>(Wk, Wv, Wq, Wb, src, dst,
                                          blockhist, pinmask, (u32*)(ws + 0));
    gemm3<<<dim3(GOFF + NWG_GEMM + NWG_LN), blk, 0, stream>>>(
        x, Wb, bk, bv, bq, Kb, Vb, Qb, blockhist, bin_off, pinmask, T,
        gamma, beta, y);
    scatter2_k<<<dim3(NB2), blk, 0, stream>>>(src, dst, blockhist, bin_off, ssrc);
    agg_k<<<dim3(NBIN), blk, 0, stream>>>(ssrc, bin_off, Qb, Kb, Vb, T, spd_w, outf, denom);
    ln_k<<<dim3(64), blk, 0, stream>>>(x, outf, denom, gamma, beta, y);
}

// Round 10
// 204.930 us; speedup vs baseline: 1.3215x; 1.3215x over previous
//
#include <hip/hip_runtime.h>
#include <stdint.h>

#define N_NODES 50000
#define E_EDGES 300000
#define C_CH    256
#define H_HEADS 8
#define NB2     64       // blocks in counting sort
#define CHUNK2  4688     // edges per sort block (64*4688 >= 300000)
#define NBIN    4096     // 256 dst x 16 src-ranges
#define SRCDIV  3125     // 50000/16 -> src-range = s/3125
#define NWG_GEMM 1568    // 391*4 (K,V m-tiles) + 4 (Q)
#define NWG_LN   12436   // (50000-256)/4 ln-tail blocks

typedef unsigned short u16;
typedef unsigned int   u32;

typedef __attribute__((ext_vector_type(8))) short  v8s;   // 8 bf16 (MFMA A/B frag)
typedef __attribute__((ext_vector_type(4))) float  v4f;   // MFMA C/D frag

__device__ __forceinline__ float bf2f(u16 v) {
    union { u32 u; float f; } x; x.u = ((u32)v) << 16; return x.f;
}
__device__ __forceinline__ u16 f2bf(float f) {
    union { float f; u32 u; } x; x.f = f;
    u32 r = (x.u + 0x7FFFu + ((x.u >> 16) & 1u)) >> 16;
    return (u16)r;
}
__device__ __forceinline__ void unp2(u32 v, float& lo, float& hi) {
    union { u32 u; float f; } x;
    x.u = v << 16; lo = x.f;
    x.u = v & 0xFFFF0000u; hi = x.f;
}
// async global->LDS, 16 B/lane; LDS dest = wave-uniform base + lane*16
__device__ __forceinline__ void gl_lds16(const u16* g, u16* l) {
    __builtin_amdgcn_global_load_lds(
        (const __attribute__((address_space(1))) void*)g,
        (__attribute__((address_space(3))) void*)l, 16, 0, 0);
}
// pack 8 fp32 -> 8 bf16, single 16B LDS store (round-4 exact)
__device__ __forceinline__ void pack8(const float4 p, const float4 q, u16* dst) {
    u16 tmp[8];
    tmp[0]=f2bf(p.x); tmp[1]=f2bf(p.y); tmp[2]=f2bf(p.z); tmp[3]=f2bf(p.w);
    tmp[4]=f2bf(q.x); tmp[5]=f2bf(q.y); tmp[6]=f2bf(q.z); tmp[7]=f2bf(q.w);
    *(uint4*)dst = *(const uint4*)tmp;
}

// ---------------------------------------------------------------------------
// prep_k: blocks 0..191 convert Wk,Wv,Wq -> bf16 Wb; blocks 192..255 run the
// (dst, src-range) histogram + per-block anchor masks (race-free: per-block
// output arrays, no global atomics into zeroed memory); blocks 256..321 zero
// the denom+outf region (replaces hipMemsetAsync).
// ---------------------------------------------------------------------------
__global__ __launch_bounds__(256) void prep_k(
    const float* __restrict__ Wk, const float* __restrict__ Wv,
    const float* __restrict__ Wq, u16* __restrict__ Wb,
    const int* __restrict__ src, const int* __restrict__ dst,
    u32* __restrict__ blockhist, u32* __restrict__ pinmask,
    u32* __restrict__ zero0)
{
    __shared__ u32 hist[NBIN];          // 16 KB
    __shared__ u32 mask[256][8];        //  8 KB
    int t = threadIdx.x, b = blockIdx.x;
    if (b < 192) {
        int m = (b < 64) ? 0 : (b < 128) ? 1 : 2;
        const float* sp = (m == 0) ? Wk : (m == 1) ? Wv : Wq;
        u16* dp = Wb + m * 65536;
        int i = (b & 63) * 1024 + t * 4;
        float4 v = *(const float4*)(sp + i);
        ushort4 o;
        o.x = f2bf(v.x); o.y = f2bf(v.y); o.z = f2bf(v.z); o.w = f2bf(v.w);
        *(ushort4*)(dp + i) = o;
        return;
    }
    if (b >= 256) {                      // zero blocks: 66 x 4096 B = 270336 B
        int z = b - 256;
        uint4 zv = make_uint4(0, 0, 0, 0);
        *(uint4*)(zero0 + z * 1024 + t * 4) = zv;
        return;
    }
    int hb = b - 192;                    // 0..63
#pragma unroll
    for (int j = 0; j < 16; j++) hist[t + j * 256] = 0;
#pragma unroll
    for (int w = 0; w < 8; w++) mask[t][w] = 0;
    __syncthreads();
    int start = hb * CHUNK2;
    int end = start + CHUNK2; if (end > E_EDGES) end = E_EDGES;
    for (int e = start + t; e < end; e += 256) {
        int d = dst[e], s = src[e];
        atomicAdd(&hist[d * 16 + s / SRCDIV], 1u);     // LDS atomic
        if (s < 256) atomicOr(&mask[d][s >> 5], 1u << (s & 31));
    }
    __syncthreads();
#pragma unroll
    for (int j = 0; j < 16; j++)
        blockhist[hb * NBIN + t + j * 256] = hist[t + j * 256];
#pragma unroll
    for (int w = 0; w < 8; w++)          // transposed: [hb][w][i], coalesced
        pinmask[hb * 2048 + w * 256 + t] = mask[t][w];
}

// ---------------------------------------------------------------------------
// Megakernel.  Blocks 0..1567: bf16 GEMM OUT[*,256] = bf16(x) @ W^T + bias —
// EXACT round-4/8 inner code (r5/r6/r7 proved every core edit at the
// 64-VGPR cliff regresses).  Block 1568 = scan, block 1569 = SPD — both with
// LOOP-INTERCHANGED reductions (b2 outer, 16/8 parallel accumulators): r9's
// j-outer form made 16 sequential 64-deep dependent-load chains = 113us
// serial pole gating the whole kernel.  Blocks 1570..: LayerNorm tail
// (nodes 256..49999).
// ---------------------------------------------------------------------------
__global__ __launch_bounds__(256, 4) void gemm3(
    const float* __restrict__ x, const u16* __restrict__ Wb,
    const float* __restrict__ bk, const float* __restrict__ bv,
    const float* __restrict__ bq,
    u16* __restrict__ Kb, u16* __restrict__ Vb, u16* __restrict__ Qb,
    const u32* __restrict__ blockhist, u32* __restrict__ bin_off,
    const u32* __restrict__ pinmask, unsigned char* __restrict__ T,
    const float* __restrict__ gamma, const float* __restrict__ beta,
    float* __restrict__ y)
{
    __shared__ u16 smem[4][128 * 32];   // A dbuf = smem[0,1], B dbuf = smem[2,3]
    const int t = threadIdx.x;

    if (blockIdx.x == NWG_GEMM) {
        // ---- scan: totals from blockhist (b2-outer, 16 parallel chains),
        //      exclusive scan -> bin_off ----
        u32* tots = (u32*)&smem[0][0];            // 16 KB
        u32* tsum = tots + NBIN;                  //  1 KB
        u32 c[16];
#pragma unroll
        for (int j = 0; j < 16; j++) c[j] = 0;
        for (int b2 = 0; b2 < NB2; b2++) {
#pragma unroll
            for (int j = 0; j < 16; j++)
                c[j] += blockhist[b2 * NBIN + j * 256 + t];
        }
#pragma unroll
        for (int j = 0; j < 16; j++) tots[j * 256 + t] = c[j];
        __syncthreads();
        u32 loc[16]; u32 a = 0;
#pragma unroll
        for (int j = 0; j < 16; j++) { loc[j] = tots[t * 16 + j]; a += loc[j]; }
        tsum[t] = a;
        __syncthreads();
        for (int off = 1; off < 256; off <<= 1) {
            u32 add = (t >= off) ? tsum[t - off] : 0u;
            __syncthreads();
            tsum[t] += add;
            __syncthreads();
        }
        u32 base = tsum[t] - a;
#pragma unroll
        for (int j = 0; j < 16; j++) { bin_off[t * 16 + j] = base; base += loc[j]; }
        if (t == 255) bin_off[NBIN] = base;
        return;
    }
    if (blockIdx.x == NWG_GEMM + 1) {
        // ---- SPD: OR per-block masks (b2-outer, 8 parallel chains),
        //      3-level reachability -> T ----
        u32* b32 = (u32*)&smem[0][0];
        u32 (*F1)[8] = (u32(*)[8])(b32);
        u32 (*F2)[8] = (u32(*)[8])(b32 + 2048);
        u32 (*F3)[8] = (u32(*)[8])(b32 + 4096);
        int i = t;
        u32 mm[8];
#pragma unroll
        for (int w = 0; w < 8; w++) mm[w] = 0;
        for (int b2 = 0; b2 < NB2; b2++) {
#pragma unroll
            for (int w = 0; w < 8; w++)
                mm[w] |= pinmask[b2 * 2048 + w * 256 + i];
        }
#pragma unroll
        for (int w = 0; w < 8; w++) { F1[i][w] = mm[w]; F2[i][w] = 0; F3[i][w] = 0; }
        __syncthreads();
        for (int w = 0; w < 8; w++) {
            u32 m = F1[i][w];
            while (m) {
                int b = __ffs(m) - 1; m &= m - 1;
                int s = w * 32 + b;
#pragma unroll
                for (int j = 0; j < 8; j++) F2[i][j] |= F1[s][j];
            }
        }
        __syncthreads();
        for (int w = 0; w < 8; w++) {
            u32 m = F1[i][w];
            while (m) {
                int b = __ffs(m) - 1; m &= m - 1;
                int s = w * 32 + b;
#pragma unroll
                for (int j = 0; j < 8; j++) F3[i][j] |= F2[s][j];
            }
        }
        __syncthreads();
        for (int w = 0; w < 8; w++) {
            u32 f1 = F1[i][w], f2 = F2[i][w], f3 = F3[i][w];
#pragma unroll
            for (int g = 0; g < 8; g++) {
                u32 word = 0;
#pragma unroll
                for (int b = 0; b < 4; b++) {
                    int bit = g * 4 + b;
                    u32 k = ((f1 >> bit) & 1u) ? 1u : ((f2 >> bit) & 1u) ? 2u
                           : ((f3 >> bit) & 1u) ? 3u : 4u;
                    word |= k << (8 * b);
                }
                *(u32*)(T + i * 256 + w * 32 + g * 4) = word;
            }
        }
        return;
    }
    if (blockIdx.x >= NWG_GEMM + 2) {
        // ---- LayerNorm tail: nodes 256..49999 (no agg contribution) ----
        int n = (blockIdx.x - (NWG_GEMM + 2)) * 4 + (t >> 6) + 256;
        int lane = t & 63;
        int ch = lane * 4;
        float4 xv = *(const float4*)(x + (size_t)n * 256 + ch);
        float h0 = xv.x, h1 = xv.y, h2 = xv.z, h3 = xv.w;
        float s = h0 + h1 + h2 + h3;
#pragma unroll
        for (int off = 1; off < 64; off <<= 1) s += __shfl_xor(s, off);
        float mu = s * (1.0f / 256.0f);
        float d0 = h0 - mu, d1 = h1 - mu, d2 = h2 - mu, d3 = h3 - mu;
        float qq = d0 * d0 + d1 * d1 + d2 * d2 + d3 * d3;
#pragma unroll
        for (int off = 1; off < 64; off <<= 1) qq += __shfl_xor(qq, off);
        float rstd = rsqrtf(qq * (1.0f / 256.0f) + 1e-5f);
        float4 gv = *(const float4*)(gamma + ch);
        float4 bv = *(const float4*)(beta + ch);
        float4 o;
        o.x = d0 * rstd * gv.x + bv.x;
        o.y = d1 * rstd * gv.y + bv.y;
        o.z = d2 * rstd * gv.z + bv.z;
        o.w = d3 * rstd * gv.w + bv.w;
        *(float4*)(y + (size_t)n * 256 + ch) = o;
        return;
    }

    // ---- GEMM (round-4 exact inner code; compact grid) ----
    // bijective XCD-chunked swizzle (nwg=1568 % 8 == 0), m-tile-major: the
    // 4 (mat,nh) K/V blocks of an m-tile share one XCD L2.
    int gid = blockIdx.x;
    int xcd = gid & 7, pos = gid >> 3;
    int wgid = xcd * (NWG_GEMM >> 3) + pos;      // 196 per XCD
    int mt, mat, nh;
    if (wgid < 1564) { mt = wgid >> 2; int j = wgid & 3; mat = j >> 1; nh = j & 1; }
    else             { int qi = wgid - 1564; mt = qi >> 1; mat = 2; nh = qi & 1; }
    const int m0 = mt * 128;
    const int M = (mat == 2) ? 256 : N_NODES;
    const u16* W = Wb + mat * 65536;
    const float* bias = (mat == 0) ? bk : (mat == 1) ? bv : bq;
    u16* OUT = (mat == 0) ? Kb : (mat == 1) ? Vb : Qb;
    const int n0 = nh * 128;

    const int lane = t & 63, w = t >> 6;
    const int quad = lane >> 4, l15 = lane & 15;
    const int mq = w & 1, nq = w >> 1;

    v4f acc[16];
#pragma unroll
    for (int i = 0; i < 16; i++) acc[i] = (v4f)(0.0f);

    const int lrow = lane >> 2;               // 0..15
    const int cg   = (lane & 3) * 8;          // fp32 col-group offset
    int rA0 = m0 + w * 32 + lrow; if (rA0 > 49999) rA0 = 49999;
    int rA1 = rA0 + 16;           if (rA1 > 49999) rA1 = 49999;
    const float* gA0 = x + (size_t)rA0 * 256 + cg;
    const float* gA1 = x + (size_t)rA1 * 256 + cg;
    const u16* gB = W + (size_t)(n0 + w * 32 + lrow) * 256 + (lane & 3) * 8;

    u16* ldsA = &smem[0][(w * 32 + lrow) * 32 + (lane & 3) * 8];

    float4 a00, a01, a10, a11;
#define LOADA(kt) do {                                   \
    a00 = *(const float4*)(gA0 + (kt) * 32);             \
    a01 = *(const float4*)(gA0 + (kt) * 32 + 4);         \
    a10 = *(const float4*)(gA1 + (kt) * 32);             \
    a11 = *(const float4*)(gA1 + (kt) * 32 + 4);         \
} while (0)
#define WRITEA(bi) do {                                  \
    pack8(a00, a01, ldsA + (bi) * 4096);                 \
    pack8(a10, a11, ldsA + (bi) * 4096 + 16 * 32);       \
} while (0)
#define STAGEB(bi, koff) do {                                             \
    gl_lds16(gB + (koff),            &smem[2 + (bi)][(w * 32) * 32]);     \
    gl_lds16(gB + 16 * 256 + (koff), &smem[2 + (bi)][(w * 32 + 16) * 32]);\
} while (0)

    LOADA(0);
    STAGEB(0, 0);
    WRITEA(0);
    __syncthreads();                          // drain prologue (vm + lgkm)
    for (int kt = 0; kt < 8; kt++) {
        const int cur = kt & 1;
        if (kt < 7) { LOADA(kt + 1); STAGEB(cur ^ 1, (kt + 1) * 32); }
        v8s a[4], b[4];
#pragma unroll
        for (int f = 0; f < 4; f++)
            a[f] = *(const v8s*)(&smem[cur][(mq * 64 + f * 16 + l15) * 32 + quad * 8]);
#pragma unroll
        for (int f = 0; f < 4; f++)
            b[f] = *(const v8s*)(&smem[2 + cur][(nq * 64 + f * 16 + l15) * 32 + quad * 8]);
#pragma unroll
        for (int fm = 0; fm < 4; fm++)
#pragma unroll
            for (int fn = 0; fn < 4; fn++)
                acc[fm * 4 + fn] = __builtin_amdgcn_mfma_f32_16x16x32_bf16(
                    a[fm], b[fn], acc[fm * 4 + fn], 0, 0, 0);
        if (kt < 7) WRITEA(cur ^ 1);          // fp32 loads landed under MFMA
        __syncthreads();                      // drains vm (B) + lgkm (A writes)
    }
#undef LOADA
#undef WRITEA
#undef STAGEB

    // Epilogue: stage C+bias into LDS (32 KB = all 4 buffers), coalesced
    // uint4 stores (full 64 B lines -> no write amplification).
    u16* S = &smem[0][0];
#pragma unroll
    for (int fn = 0; fn < 4; fn++) {
        int n = nq * 64 + fn * 16 + l15;
        float bi = bias[n0 + n];
#pragma unroll
        for (int fm = 0; fm < 4; fm++) {
#pragma unroll
            for (int r2 = 0; r2 < 4; r2++) {
                int row = mq * 64 + fm * 16 + quad * 4 + r2;
                S[row * 128 + n] = f2bf(acc[fm * 4 + fn][r2] + bi);
            }
        }
    }
    __syncthreads();
#pragma unroll
    for (int i = 0; i < 8; i++) {
        int c = i * 256 + t;
        int row = c >> 4;
        int m = m0 + row;
        if (m < M)
            *(uint4*)(OUT + (size_t)m * 256 + n0 + (c & 15) * 8) =
                *(const uint4*)(S + c * 8);
    }
}

// ---------------------------------------------------------------------------
// Sort pass 3 (16 blocks): per-(sortblock,bin) base = bin_off + block prefix.
// All 64 histogram values prefetched into regs (one latency), prefix in regs.
// ---------------------------------------------------------------------------
__global__ __launch_bounds__(256) void base_k(
    const u32* __restrict__ blockhist, const u32* __restrict__ bin_off,
    u32* __restrict__ blockbase)
{
    int bin = blockIdx.x * 256 + threadIdx.x;
    u32 h[NB2];
#pragma unroll
    for (int b = 0; b < NB2; b++) h[b] = blockhist[b * NBIN + bin];
    u32 run = bin_off[bin];
#pragma unroll
    for (int b = 0; b < NB2; b++) {
        blockbase[b * NBIN + bin] = run;
        run += h[b];
    }
}

// ---------------------------------------------------------------------------
// Sort pass 4: scatter SRC VALUES into (dst, src-range) buckets (LDS cursors).
// ---------------------------------------------------------------------------
__global__ __launch_bounds__(256) void scatter2_k(
    const int* __restrict__ src, const int* __restrict__ dst,
    const u32* __restrict__ blockbase, u32* __restrict__ ssrc)
{
    __shared__ u32 cur[NBIN];
    int t = threadIdx.x, b = blockIdx.x;
#pragma unroll
    for (int j = 0; j < 16; j++)
        cur[t + j * 256] = blockbase[b * NBIN + t + j * 256];
    __syncthreads();
    int start = b * CHUNK2;
    int end = start + CHUNK2; if (end > E_EDGES) end = E_EDGES;
    for (int e = start + t; e < end; e += 256) {
        int s = src[e];
        int bin = dst[e] * 16 + s / SRCDIV;
        u32 pos = atomicAdd(&cur[bin], 1u);   // LDS atomic
        ssrc[pos] = (u32)s;
    }
}

// ---------------------------------------------------------------------------
// Fused scores+aggregate.  blockIdx = d*16 + src-range p -> each block's K/V
// gather stays inside a 3.2 MB src window; blockIdx%8 == p%8 pins a window
// pair per XCD L2.  2-deep pipeline: src 2 iters ahead, K/V rows 1 ahead.
// ---------------------------------------------------------------------------
__global__ __launch_bounds__(256) void agg_k(
    const u32* __restrict__ ssrc, const u32* __restrict__ bin_off,
    const u16* __restrict__ Qb, const u16* __restrict__ Kb,
    const u16* __restrict__ Vb, const unsigned char* __restrict__ T,
    const float* __restrict__ spd_w, float* __restrict__ out,
    float* __restrict__ denom)
{
    __shared__ float red[4 * 256];
    __shared__ float dred[4 * 8];
    int bid = blockIdx.x;
    int d = bid >> 4;
    int t = threadIdx.x, lane = t & 63, wave = t >> 6;
    int half = lane >> 5, sl = lane & 31;
    int h = sl >> 2;                        // head = (sl*8)>>5
    u32 start = bin_off[bid], end = bin_off[bid + 1];

    uint4 qv = *(const uint4*)(Qb + (size_t)d * 256 + sl * 8);
    float q0,q1,q2,q3,q4,q5,q6,q7;
    unp2(qv.x,q0,q1); unp2(qv.y,q2,q3); unp2(qv.z,q4,q5); unp2(qv.w,q6,q7);
    float sw4 = spd_w[4 * 8 + h];           // spd=4 bias (src>=256, ~98.5%)

    float a0=0.f,a1=0.f,a2=0.f,a3=0.f,a4=0.f,a5=0.f,a6=0.f,a7=0.f,dsum=0.f;

    u32 i = start + (u32)(wave * 2 + half);  // 8 slots, stride 8
    int s_c = 0, s_n = 0;
    uint4 kv_c = make_uint4(0,0,0,0), vv_c = kv_c;
    if (i < end) {
        s_c = (int)ssrc[i];
        kv_c = *(const uint4*)(Kb + (size_t)s_c * 256 + sl * 8);
        vv_c = *(const uint4*)(Vb + (size_t)s_c * 256 + sl * 8);
        if (i + 8 < end) s_n = (int)ssrc[i + 8];
    }
    while (i < end) {
        u32 inx = i + 8;
        uint4 kv_n = kv_c, vv_n = vv_c;
        if (inx < end) {                    // issue next row loads (addr ready)
            kv_n = *(const uint4*)(Kb + (size_t)s_n * 256 + sl * 8);
            vv_n = *(const uint4*)(Vb + (size_t)s_n * 256 + sl * 8);
        }
        int s_nn = (inx + 8 < end) ? (int)ssrc[inx + 8] : 0;
        float k0,k1,k2,k3,k4,k5,k6,k7, v0,v1,v2,v3,v4,v5,v6,v7;
        unp2(kv_c.x,k0,k1); unp2(kv_c.y,k2,k3); unp2(kv_c.z,k4,k5); unp2(kv_c.w,k6,k7);
        unp2(vv_c.x,v0,v1); unp2(vv_c.y,v2,v3); unp2(vv_c.z,v4,v5); unp2(vv_c.w,v6,v7);
        float p = q0*k0+q1*k1+q2*k2+q3*k3+q4*k4+q5*k5+q6*k6+q7*k7;
        p += __shfl_xor(p, 1);
        p += __shfl_xor(p, 2);              // head dot over 4 lanes x 8 ch
        float bias = (s_c < 256) ? spd_w[(int)T[s_c * 256 + d] * 8 + h] : sw4;
        float wgt = __expf(p * 0.17677669529663689f + bias);
        a0 += wgt*v0; a1 += wgt*v1; a2 += wgt*v2; a3 += wgt*v3;
        a4 += wgt*v4; a5 += wgt*v5; a6 += wgt*v6; a7 += wgt*v7;
        if ((sl & 3) == 0) dsum += wgt;
        i = inx; s_c = s_n; s_n = s_nn; kv_c = kv_n; vv_c = vv_n;
    }
    a0 += __shfl_xor(a0,32); a1 += __shfl_xor(a1,32);
    a2 += __shfl_xor(a2,32); a3 += __shfl_xor(a3,32);
    a4 += __shfl_xor(a4,32); a5 += __shfl_xor(a5,32);
    a6 += __shfl_xor(a6,32); a7 += __shfl_xor(a7,32);
    dsum += __shfl_xor(dsum,32);
    if (half == 0) {
        *(float4*)(&red[wave * 256 + sl * 8])     = make_float4(a0,a1,a2,a3);
        *(float4*)(&red[wave * 256 + sl * 8 + 4]) = make_float4(a4,a5,a6,a7);
        if ((sl & 3) == 0) dred[wave * 8 + h] = dsum;
    }
    __syncthreads();
    float sAll = red[t] + red[256 + t] + red[512 + t] + red[768 + t];
    atomicAdd(&out[(size_t)d * 256 + t], sAll);
    if (t < 8) {
        float ds = dred[t] + dred[8 + t] + dred[16 + t] + dred[24 + t];
        atomicAdd(&denom[d * 8 + t], ds);
    }
}

// ---------------------------------------------------------------------------
// LayerNorm anchors (n < 256 only): h = out/denom + x.  Tail nodes were
// normalized inside the megakernel.  64 blocks.
// ---------------------------------------------------------------------------
__global__ __launch_bounds__(256) void ln_k(
    const float* __restrict__ x, const float* __restrict__ out,
    const float* __restrict__ denom, const float* __restrict__ gamma,
    const float* __restrict__ beta, float* __restrict__ y)
{
    int n = blockIdx.x * 4 + (threadIdx.x >> 6);
    int lane = threadIdx.x & 63;
    int ch = lane * 4;
    float4 xv = *(const float4*)(x + (size_t)n * 256 + ch);
    float h0 = xv.x, h1 = xv.y, h2 = xv.z, h3 = xv.w;
    float den = denom[n * 8 + (lane >> 3)];
    float inv = (den > 0.f) ? 1.0f / den : 0.0f;
    const float* op = out + (size_t)n * 256 + ch;
    h0 += op[0] * inv; h1 += op[1] * inv;
    h2 += op[2] * inv; h3 += op[3] * inv;
    float s = h0 + h1 + h2 + h3;
#pragma unroll
    for (int off = 1; off < 64; off <<= 1) s += __shfl_xor(s, off);
    float mu = s * (1.0f / 256.0f);
    float d0 = h0 - mu, d1 = h1 - mu, d2 = h2 - mu, d3 = h3 - mu;
    float q = d0 * d0 + d1 * d1 + d2 * d2 + d3 * d3;
#pragma unroll
    for (int off = 1; off < 64; off <<= 1) q += __shfl_xor(q, off);
    float rstd = rsqrtf(q * (1.0f / 256.0f) + 1e-5f);
    float4 gv = *(const float4*)(gamma + ch);
    float4 bv = *(const float4*)(beta + ch);
    float4 o;
    o.x = d0 * rstd * gv.x + bv.x;
    o.y = d1 * rstd * gv.y + bv.y;
    o.z = d2 * rstd * gv.z + bv.z;
    o.w = d3 * rstd * gv.w + bv.w;
    *(float4*)(y + (size_t)n * 256 + ch) = o;
}

// ---------------------------------------------------------------------------
extern "C" void kernel_launch(void* const* d_in, const int* in_sizes, int n_in,
                              void* d_out, int out_size, void* d_ws, size_t ws_size,
                              hipStream_t stream)
{
    const float* x     = (const float*)d_in[0];
    const int*   src   = (const int*)d_in[1];
    const int*   dst   = (const int*)d_in[2];
    const float* Wq    = (const float*)d_in[3];
    const float* bq    = (const float*)d_in[4];
    const float* Wk    = (const float*)d_in[5];
    const float* bk    = (const float*)d_in[6];
    const float* Wv    = (const float*)d_in[7];
    const float* bv    = (const float*)d_in[8];
    const float* spd_w = (const float*)d_in[9];
    const float* gamma = (const float*)d_in[10];
    const float* beta  = (const float*)d_in[11];
    float* y = (float*)d_out;

    char* ws = (char*)d_ws;
    // denom+outf zeroed by prep_k zero-blocks (270336 B from ws+0).
    float* denom     = (float*)(ws + 0);          //   8192 B
    float* outf      = (float*)(ws + 8192);       // 262144 B -> 270336
    u32*   bin_off   = (u32*)(ws + 270336);       //  16388 B (pad) -> 286976
    unsigned char* T = (unsigned char*)(ws + 286976); // 65536 B -> 352512
    u32*   blockhist = (u32*)(ws + 352512);       // 64*4096*4 = 1 MB -> 1401088
    u32*   pinmask   = (u32*)(ws + 1401088);      // 64*2048*4 = 512 KB -> 1925376
    u32*   blockbase = (u32*)(ws + 1925376);      // 1 MB -> 2973952
    u32*   ssrc      = (u32*)(ws + 2973952);      // 1.2 MB -> 4202752
    u16*   Qb        = (u16*)(ws + 4202752);      // 128 KB -> 4333824
    u16*   Kb        = (u16*)(ws + 4333824);      // 25.6 MB -> 29933824
    u16*   Vb        = (u16*)(ws + 29933824);     // 25.6 MB -> 55533824
    u16*   Wb        = (u16*)(ws + 55533824);     // 384 KB (end ~55.9 MB)

    dim3 blk(256);
    prep_k<<<dim3(322), blk, 0, stream>>>(Wk, Wv, Wq, Wb, src, dst,
                                          blockhist, pinmask, (u32*)(ws + 0));
    gemm3<<<dim3(NWG_GEMM + 2 + NWG_LN), blk, 0, stream>>>(
        x, Wb, bk, bv, bq, Kb, Vb, Qb, blockhist, bin_off, pinmask, T,
        gamma, beta, y);
    base_k<<<dim3(16), blk, 0, stream>>>(blockhist, bin_off, blockbase);
    scatter2_k<<<dim3(NB2), blk, 0, stream>>>(src, dst, blockbase, ssrc);
    agg_k<<<dim3(NBIN), blk, 0, stream>>>(ssrc, bin_off, Qb, Kb, Vb, T, spd_w, outf, denom);
    ln_k<<<dim3(64), blk, 0, stream>>>(x, outf, denom, gamma, beta, y);
}

// Round 11
// 200.733 us; speedup vs baseline: 1.3491x; 1.0209x over previous
//
#include <hip/hip_runtime.h>
#include <stdint.h>

#define N_NODES 50000
#define E_EDGES 300000
#define C_CH    256
#define H_HEADS 8
#define NB2     64       // blocks in counting sort
#define CHUNK2  4688     // edges per sort block (64*4688 >= 300000)
#define NBIN    4096     // 256 dst x 16 src-ranges
#define SRCDIV  3125     // 50000/16 -> src-range = s/3125
#define NWG_GEMM 1568    // 391*4 (K,V m-tiles) + 4 (Q)
#define NWG_LN   12436   // (50000-256)/4 ln-tail blocks
#define GOFF     2       // gemm blocks start at blockIdx 2 (0=scan, 1=SPD)

typedef unsigned short u16;
typedef unsigned int   u32;

typedef __attribute__((ext_vector_type(8))) short  v8s;   // 8 bf16 (MFMA A/B frag)
typedef __attribute__((ext_vector_type(4))) float  v4f;   // MFMA C/D frag

__device__ __forceinline__ float bf2f(u16 v) {
    union { u32 u; float f; } x; x.u = ((u32)v) << 16; return x.f;
}
__device__ __forceinline__ u16 f2bf(float f) {
    union { float f; u32 u; } x; x.f = f;
    u32 r = (x.u + 0x7FFFu + ((x.u >> 16) & 1u)) >> 16;
    return (u16)r;
}
__device__ __forceinline__ void unp2(u32 v, float& lo, float& hi) {
    union { u32 u; float f; } x;
    x.u = v << 16; lo = x.f;
    x.u = v & 0xFFFF0000u; hi = x.f;
}
// async global->LDS, 16 B/lane; LDS dest = wave-uniform base + lane*16
__device__ __forceinline__ void gl_lds16(const u16* g, u16* l) {
    __builtin_amdgcn_global_load_lds(
        (const __attribute__((address_space(1))) void*)g,
        (__attribute__((address_space(3))) void*)l, 16, 0, 0);
}
// pack 8 fp32 -> 8 bf16, single 16B LDS store (round-4 exact)
__device__ __forceinline__ void pack8(const float4 p, const float4 q, u16* dst) {
    u16 tmp[8];
    tmp[0]=f2bf(p.x); tmp[1]=f2bf(p.y); tmp[2]=f2bf(p.z); tmp[3]=f2bf(p.w);
    tmp[4]=f2bf(q.x); tmp[5]=f2bf(q.y); tmp[6]=f2bf(q.z); tmp[7]=f2bf(q.w);
    *(uint4*)dst = *(const uint4*)tmp;
}

// ---------------------------------------------------------------------------
// prep_k: blocks 0..191 convert Wk,Wv,Wq -> bf16 Wb; blocks 192..255 run the
// (dst, src-range) histogram + per-block anchor masks (race-free: per-block
// output arrays, no global atomics into zeroed memory); blocks 256..321 zero
// the denom+outf region (replaces hipMemsetAsync).
// ---------------------------------------------------------------------------
__global__ __launch_bounds__(256) void prep_k(
    const float* __restrict__ Wk, const float* __restrict__ Wv,
    const float* __restrict__ Wq, u16* __restrict__ Wb,
    const int* __restrict__ src, const int* __restrict__ dst,
    u32* __restrict__ blockhist, u32* __restrict__ pinmask,
    u32* __restrict__ zero0)
{
    __shared__ u32 hist[NBIN];          // 16 KB
    __shared__ u32 mask[256][8];        //  8 KB
    int t = threadIdx.x, b = blockIdx.x;
    if (b < 192) {
        int m = (b < 64) ? 0 : (b < 128) ? 1 : 2;
        const float* sp = (m == 0) ? Wk : (m == 1) ? Wv : Wq;
        u16* dp = Wb + m * 65536;
        int i = (b & 63) * 1024 + t * 4;
        float4 v = *(const float4*)(sp + i);
        ushort4 o;
        o.x = f2bf(v.x); o.y = f2bf(v.y); o.z = f2bf(v.z); o.w = f2bf(v.w);
        *(ushort4*)(dp + i) = o;
        return;
    }
    if (b >= 256) {                      // zero blocks: 66 x 4096 B = 270336 B
        int z = b - 256;
        uint4 zv = make_uint4(0, 0, 0, 0);
        *(uint4*)(zero0 + z * 1024 + t * 4) = zv;
        return;
    }
    int hb = b - 192;                    // 0..63
#pragma unroll
    for (int j = 0; j < 16; j++) hist[t + j * 256] = 0;
#pragma unroll
    for (int w = 0; w < 8; w++) mask[t][w] = 0;
    __syncthreads();
    int start = hb * CHUNK2;
    int end = start + CHUNK2; if (end > E_EDGES) end = E_EDGES;
    for (int e = start + t; e < end; e += 256) {
        int d = dst[e], s = src[e];
        atomicAdd(&hist[d * 16 + s / SRCDIV], 1u);     // LDS atomic
        if (s < 256) atomicOr(&mask[d][s >> 5], 1u << (s & 31));
    }
    __syncthreads();
#pragma unroll
    for (int j = 0; j < 16; j++)
        blockhist[hb * NBIN + t + j * 256] = hist[t + j * 256];
#pragma unroll
    for (int w = 0; w < 8; w++)          // transposed: [hb][w][i], coalesced
        pinmask[hb * 2048 + w * 256 + t] = mask[t][w];
}

// ---------------------------------------------------------------------------
// Megakernel.  Block 0 = scan, block 1 = SPD — FIRST in dispatch order so
// they start at t=0 and their ~20us 1-block reductions hide under the gemm
// span (r10 placed them at 1568/1569, BEHIND the 1024-block initial wave ->
// they ran nearly alone as a 30us low-occupancy tail: 86.5us vs r8's 53.6).
// Both use loop-interchanged reductions (b2 outer, 16/8 parallel chains —
// r9's j-outer form was a 113us serial pole).  Blocks 2..1569: bf16 GEMM
// OUT[*,256] = bf16(x) @ W^T + bias — EXACT round-4/8 inner code (r5/r6/r7
// proved every core edit at the 64-VGPR cliff regresses).  Blocks 1570..:
// LayerNorm tail (nodes 256..49999).
// ---------------------------------------------------------------------------
__global__ __launch_bounds__(256, 4) void gemm3(
    const float* __restrict__ x, const u16* __restrict__ Wb,
    const float* __restrict__ bk, const float* __restrict__ bv,
    const float* __restrict__ bq,
    u16* __restrict__ Kb, u16* __restrict__ Vb, u16* __restrict__ Qb,
    const u32* __restrict__ blockhist, u32* __restrict__ bin_off,
    const u32* __restrict__ pinmask, unsigned char* __restrict__ T,
    const float* __restrict__ gamma, const float* __restrict__ beta,
    float* __restrict__ y)
{
    __shared__ u16 smem[4][128 * 32];   // A dbuf = smem[0,1], B dbuf = smem[2,3]
    const int t = threadIdx.x;

    if (blockIdx.x == 0) {
        // ---- scan: totals from blockhist (b2-outer, 16 parallel chains),
        //      exclusive scan -> bin_off ----
        u32* tots = (u32*)&smem[0][0];            // 16 KB
        u32* tsum = tots + NBIN;                  //  1 KB
        u32 c[16];
#pragma unroll
        for (int j = 0; j < 16; j++) c[j] = 0;
        for (int b2 = 0; b2 < NB2; b2++) {
#pragma unroll
            for (int j = 0; j < 16; j++)
                c[j] += blockhist[b2 * NBIN + j * 256 + t];
        }
#pragma unroll
        for (int j = 0; j < 16; j++) tots[j * 256 + t] = c[j];
        __syncthreads();
        u32 loc[16]; u32 a = 0;
#pragma unroll
        for (int j = 0; j < 16; j++) { loc[j] = tots[t * 16 + j]; a += loc[j]; }
        tsum[t] = a;
        __syncthreads();
        for (int off = 1; off < 256; off <<= 1) {
            u32 add = (t >= off) ? tsum[t - off] : 0u;
            __syncthreads();
            tsum[t] += add;
            __syncthreads();
        }
        u32 base = tsum[t] - a;
#pragma unroll
        for (int j = 0; j < 16; j++) { bin_off[t * 16 + j] = base; base += loc[j]; }
        if (t == 255) bin_off[NBIN] = base;
        return;
    }
    if (blockIdx.x == 1) {
        // ---- SPD: OR per-block masks (b2-outer, 8 parallel chains),
        //      3-level reachability -> T ----
        u32* b32 = (u32*)&smem[0][0];
        u32 (*F1)[8] = (u32(*)[8])(b32);
        u32 (*F2)[8] = (u32(*)[8])(b32 + 2048);
        u32 (*F3)[8] = (u32(*)[8])(b32 + 4096);
        int i = t;
        u32 mm[8];
#pragma unroll
        for (int w = 0; w < 8; w++) mm[w] = 0;
        for (int b2 = 0; b2 < NB2; b2++) {
#pragma unroll
            for (int w = 0; w < 8; w++)
                mm[w] |= pinmask[b2 * 2048 + w * 256 + i];
        }
#pragma unroll
        for (int w = 0; w < 8; w++) { F1[i][w] = mm[w]; F2[i][w] = 0; F3[i][w] = 0; }
        __syncthreads();
        for (int w = 0; w < 8; w++) {
            u32 m = F1[i][w];
            while (m) {
                int b = __ffs(m) - 1; m &= m - 1;
                int s = w * 32 + b;
#pragma unroll
                for (int j = 0; j < 8; j++) F2[i][j] |= F1[s][j];
            }
        }
        __syncthreads();
        for (int w = 0; w < 8; w++) {
            u32 m = F1[i][w];
            while (m) {
                int b = __ffs(m) - 1; m &= m - 1;
                int s = w * 32 + b;
#pragma unroll
                for (int j = 0; j < 8; j++) F3[i][j] |= F2[s][j];
            }
        }
        __syncthreads();
        for (int w = 0; w < 8; w++) {
            u32 f1 = F1[i][w], f2 = F2[i][w], f3 = F3[i][w];
#pragma unroll
            for (int g = 0; g < 8; g++) {
                u32 word = 0;
#pragma unroll
                for (int b = 0; b < 4; b++) {
                    int bit = g * 4 + b;
                    u32 k = ((f1 >> bit) & 1u) ? 1u : ((f2 >> bit) & 1u) ? 2u
                           : ((f3 >> bit) & 1u) ? 3u : 4u;
                    word |= k << (8 * b);
                }
                *(u32*)(T + i * 256 + w * 32 + g * 4) = word;
            }
        }
        return;
    }
    if (blockIdx.x >= GOFF + NWG_GEMM) {
        // ---- LayerNorm tail: nodes 256..49999 (no agg contribution) ----
        int n = (blockIdx.x - (GOFF + NWG_GEMM)) * 4 + (t >> 6) + 256;
        int lane = t & 63;
        int ch = lane * 4;
        float4 xv = *(const float4*)(x + (size_t)n * 256 + ch);
        float h0 = xv.x, h1 = xv.y, h2 = xv.z, h3 = xv.w;
        float s = h0 + h1 + h2 + h3;
#pragma unroll
        for (int off = 1; off < 64; off <<= 1) s += __shfl_xor(s, off);
        float mu = s * (1.0f / 256.0f);
        float d0 = h0 - mu, d1 = h1 - mu, d2 = h2 - mu, d3 = h3 - mu;
        float qq = d0 * d0 + d1 * d1 + d2 * d2 + d3 * d3;
#pragma unroll
        for (int off = 1; off < 64; off <<= 1) qq += __shfl_xor(qq, off);
        float rstd = rsqrtf(qq * (1.0f / 256.0f) + 1e-5f);
        float4 gv = *(const float4*)(gamma + ch);
        float4 bv = *(const float4*)(beta + ch);
        float4 o;
        o.x = d0 * rstd * gv.x + bv.x;
        o.y = d1 * rstd * gv.y + bv.y;
        o.z = d2 * rstd * gv.z + bv.z;
        o.w = d3 * rstd * gv.w + bv.w;
        *(float4*)(y + (size_t)n * 256 + ch) = o;
        return;
    }

    // ---- GEMM (round-4 exact inner code; compact grid) ----
    // bijective XCD-chunked swizzle (nwg=1568 % 8 == 0), m-tile-major: the
    // 4 (mat,nh) K/V blocks of an m-tile share one XCD L2.
    int gid = blockIdx.x - GOFF;
    int xcd = gid & 7, pos = gid >> 3;
    int wgid = xcd * (NWG_GEMM >> 3) + pos;      // 196 per XCD
    int mt, mat, nh;
    if (wgid < 1564) { mt = wgid >> 2; int j = wgid & 3; mat = j >> 1; nh = j & 1; }
    else             { int qi = wgid - 1564; mt = qi >> 1; mat = 2; nh = qi & 1; }
    const int m0 = mt * 128;
    const int M = (mat == 2) ? 256 : N_NODES;
    const u16* W = Wb + mat * 65536;
    const float* bias = (mat == 0) ? bk : (mat == 1) ? bv : bq;
    u16* OUT = (mat == 0) ? Kb : (mat == 1) ? Vb : Qb;
    const int n0 = nh * 128;

    const int lane = t & 63, w = t >> 6;
    const int quad = lane >> 4, l15 = lane & 15;
    const int mq = w & 1, nq = w >> 1;

    v4f acc[16];
#pragma unroll
    for (int i = 0; i < 16; i++) acc[i] = (v4f)(0.0f);

    const int lrow = lane >> 2;               // 0..15
    const int cg   = (lane & 3) * 8;          // fp32 col-group offset
    int rA0 = m0 + w * 32 + lrow; if (rA0 > 49999) rA0 = 49999;
    int rA1 = rA0 + 16;           if (rA1 > 49999) rA1 = 49999;
    const float* gA0 = x + (size_t)rA0 * 256 + cg;
    const float* gA1 = x + (size_t)rA1 * 256 + cg;
    const u16* gB = W + (size_t)(n0 + w * 32 + lrow) * 256 + (lane & 3) * 8;

    u16* ldsA = &smem[0][(w * 32 + lrow) * 32 + (lane & 3) * 8];

    float4 a00, a01, a10, a11;
#define LOADA(kt) do {                                   \
    a00 = *(const float4*)(gA0 + (kt) * 32);             \
    a01 = *(const float4*)(gA0 + (kt) * 32 + 4);         \
    a10 = *(const float4*)(gA1 + (kt) * 32);             \
    a11 = *(const float4*)(gA1 + (kt) * 32 + 4);         \
} while (0)
#define WRITEA(bi) do {                                  \
    pack8(a00, a01, ldsA + (bi) * 4096);                 \
    pack8(a10, a11, ldsA + (bi) * 4096 + 16 * 32);       \
} while (0)
#define STAGEB(bi, koff) do {                                             \
    gl_lds16(gB + (koff),            &smem[2 + (bi)][(w * 32) * 32]);     \
    gl_lds16(gB + 16 * 256 + (koff), &smem[2 + (bi)][(w * 32 + 16) * 32]);\
} while (0)

    LOADA(0);
    STAGEB(0, 0);
    WRITEA(0);
    __syncthreads();                          // drain prologue (vm + lgkm)
    for (int kt = 0; kt < 8; kt++) {
        const int cur = kt & 1;
        if (kt < 7) { LOADA(kt + 1); STAGEB(cur ^ 1, (kt + 1) * 32); }
        v8s a[4], b[4];
#pragma unroll
        for (int f = 0; f < 4; f++)
            a[f] = *(const v8s*)(&smem[cur][(mq * 64 + f * 16 + l15) * 32 + quad * 8]);
#pragma unroll
        for (int f = 0; f < 4; f++)
            b[f] = *(const v8s*)(&smem[2 + cur][(nq * 64 + f * 16 + l15) * 32 + quad * 8]);
#pragma unroll
        for (int fm = 0; fm < 4; fm++)
#pragma unroll
            for (int fn = 0; fn < 4; fn++)
                acc[fm * 4 + fn] = __builtin_amdgcn_mfma_f32_16x16x32_bf16(
                    a[fm], b[fn], acc[fm * 4 + fn], 0, 0, 0);
        if (kt < 7) WRITEA(cur ^ 1);          // fp32 loads landed under MFMA
        __syncthreads();                      // drains vm (B) + lgkm (A writes)
    }
#undef LOADA
#undef WRITEA
#undef STAGEB

    // Epilogue: stage C+bias into LDS (32 KB = all 4 buffers), coalesced
    // uint4 stores (full 64 B lines -> no write amplification).
    u16* S = &smem[0][0];
#pragma unroll
    for (int fn = 0; fn < 4; fn++) {
        int n = nq * 64 + fn * 16 + l15;
        float bi = bias[n0 + n];
#pragma unroll
        for (int fm = 0; fm < 4; fm++) {
#pragma unroll
            for (int r2 = 0; r2 < 4; r2++) {
                int row = mq * 64 + fm * 16 + quad * 4 + r2;
                S[row * 128 + n] = f2bf(acc[fm * 4 + fn][r2] + bi);
            }
        }
    }
    __syncthreads();
#pragma unroll
    for (int i = 0; i < 8; i++) {
        int c = i * 256 + t;
        int row = c >> 4;
        int m = m0 + row;
        if (m < M)
            *(uint4*)(OUT + (size_t)m * 256 + n0 + (c & 15) * 8) =
                *(const uint4*)(S + c * 8);
    }
}

// ---------------------------------------------------------------------------
// Sort pass 3 (16 blocks): per-(sortblock,bin) base = bin_off + block prefix.
// All 64 histogram values prefetched into regs (one latency), prefix in regs.
// ---------------------------------------------------------------------------
__global__ __launch_bounds__(256) void base_k(
    const u32* __restrict__ blockhist, const u32* __restrict__ bin_off,
    u32* __restrict__ blockbase)
{
    int bin = blockIdx.x * 256 + threadIdx.x;
    u32 h[NB2];
#pragma unroll
    for (int b = 0; b < NB2; b++) h[b] = blockhist[b * NBIN + bin];
    u32 run = bin_off[bin];
#pragma unroll
    for (int b = 0; b < NB2; b++) {
        blockbase[b * NBIN + bin] = run;
        run += h[b];
    }
}

// ---------------------------------------------------------------------------
// Sort pass 4: scatter SRC VALUES into (dst, src-range) buckets (LDS cursors).
// ---------------------------------------------------------------------------
__global__ __launch_bounds__(256) void scatter2_k(
    const int* __restrict__ src, const int* __restrict__ dst,
    const u32* __restrict__ blockbase, u32* __restrict__ ssrc)
{
    __shared__ u32 cur[NBIN];
    int t = threadIdx.x, b = blockIdx.x;
#pragma unroll
    for (int j = 0; j < 16; j++)
        cur[t + j * 256] = blockbase[b * NBIN + t + j * 256];
    __syncthreads();
    int start = b * CHUNK2;
    int end = start + CHUNK2; if (end > E_EDGES) end = E_EDGES;
    for (int e = start + t; e < end; e += 256) {
        int s = src[e];
        int bin = dst[e] * 16 + s / SRCDIV;
        u32 pos = atomicAdd(&cur[bin], 1u);   // LDS atomic
        ssrc[pos] = (u32)s;
    }
}

// ---------------------------------------------------------------------------
// Fused scores+aggregate.  blockIdx = d*16 + src-range p -> each block's K/V
// gather stays inside a 3.2 MB src window; blockIdx%8 == p%8 pins a window
// pair per XCD L2.  2-deep pipeline: src 2 iters ahead, K/V rows 1 ahead.
// ---------------------------------------------------------------------------
__global__ __launch_bounds__(256) void agg_k(
    const u32* __restrict__ ssrc, const u32* __restrict__ bin_off,
    const u16* __restrict__ Qb, const u16* __restrict__ Kb,
    const u16* __restrict__ Vb, const unsigned char* __restrict__ T,
    const float* __restrict__ spd_w, float* __restrict__ out,
    float* __restrict__ denom)
{
    __shared__ float red[4 * 256];
    __shared__ float dred[4 * 8];
    int bid = blockIdx.x;
    int d = bid >> 4;
    int t = threadIdx.x, lane = t & 63, wave = t >> 6;
    int half = lane >> 5, sl = lane & 31;
    int h = sl >> 2;                        // head = (sl*8)>>5
    u32 start = bin_off[bid], end = bin_off[bid + 1];

    uint4 qv = *(const uint4*)(Qb + (size_t)d * 256 + sl * 8);
    float q0,q1,q2,q3,q4,q5,q6,q7;
    unp2(qv.x,q0,q1); unp2(qv.y,q2,q3); unp2(qv.z,q4,q5); unp2(qv.w,q6,q7);
    float sw4 = spd_w[4 * 8 + h];           // spd=4 bias (src>=256, ~98.5%)

    float a0=0.f,a1=0.f,a2=0.f,a3=0.f,a4=0.f,a5=0.f,a6=0.f,a7=0.f,dsum=0.f;

    u32 i = start + (u32)(wave * 2 + half);  // 8 slots, stride 8
    int s_c = 0, s_n = 0;
    uint4 kv_c = make_uint4(0,0,0,0), vv_c = kv_c;
    if (i < end) {
        s_c = (int)ssrc[i];
        kv_c = *(const uint4*)(Kb + (size_t)s_c * 256 + sl * 8);
        vv_c = *(const uint4*)(Vb + (size_t)s_c * 256 + sl * 8);
        if (i + 8 < end) s_n = (int)ssrc[i + 8];
    }
    while (i < end) {
        u32 inx = i + 8;
        uint4 kv_n = kv_c, vv_n = vv_c;
        if (inx < end) {                    // issue next row loads (addr ready)
            kv_n = *(const uint4*)(Kb + (size_t)s_n * 256 + sl * 8);
            vv_n = *(const uint4*)(Vb + (size_t)s_n * 256 + sl * 8);
        }
        int s_nn = (inx + 8 < end) ? (int)ssrc[inx + 8] : 0;
        float k0,k1,k2,k3,k4,k5,k6,k7, v0,v1,v2,v3,v4,v5,v6,v7;
        unp2(kv_c.x,k0,k1); unp2(kv_c.y,k2,k3); unp2(kv_c.z,k4,k5); unp2(kv_c.w,k6,k7);
        unp2(vv_c.x,v0,v1); unp2(vv_c.y,v2,v3); unp2(vv_c.z,v4,v5); unp2(vv_c.w,v6,v7);
        float p = q0*k0+q1*k1+q2*k2+q3*k3+q4*k4+q5*k5+q6*k6+q7*k7;
        p += __shfl_xor(p, 1);
        p += __shfl_xor(p, 2);              // head dot over 4 lanes x 8 ch
        float bias = (s_c < 256) ? spd_w[(int)T[s_c * 256 + d] * 8 + h] : sw4;
        float wgt = __expf(p * 0.17677669529663689f + bias);
        a0 += wgt*v0; a1 += wgt*v1; a2 += wgt*v2; a3 += wgt*v3;
        a4 += wgt*v4; a5 += wgt*v5; a6 += wgt*v6; a7 += wgt*v7;
        if ((sl & 3) == 0) dsum += wgt;
        i = inx; s_c = s_n; s_n = s_nn; kv_c = kv_n; vv_c = vv_n;
    }
    a0 += __shfl_xor(a0,32); a1 += __shfl_xor(a1,32);
    a2 += __shfl_xor(a2,32); a3 += __shfl_xor(a3,32);
    a4 += __shfl_xor(a4,32); a5 += __shfl_xor(a5,32);
    a6 += __shfl_xor(a6,32); a7 += __shfl_xor(a7,32);
    dsum += __shfl_xor(dsum,32);
    if (half == 0) {
        *(float4*)(&red[wave * 256 + sl * 8])     = make_float4(a0,a1,a2,a3);
        *(float4*)(&red[wave * 256 + sl * 8 + 4]) = make_float4(a4,a5,a6,a7);
        if ((sl & 3) == 0) dred[wave * 8 + h] = dsum;
    }
    __syncthreads();
    float sAll = red[t] + red[256 + t] + red[512 + t] + red[768 + t];
    atomicAdd(&out[(size_t)d * 256 + t], sAll);
    if (t < 8) {
        float ds = dred[t] + dred[8 + t] + dred[16 + t] + dred[24 + t];
        atomicAdd(&denom[d * 8 + t], ds);
    }
}

// ---------------------------------------------------------------------------
// LayerNorm anchors (n < 256 only): h = out/denom + x.  Tail nodes were
// normalized inside the megakernel.  64 blocks.
// ---------------------------------------------------------------------------
__global__ __launch_bounds__(256) void ln_k(
    const float* __restrict__ x, const float* __restrict__ out,
    const float* __restrict__ denom, const float* __restrict__ gamma,
    const float* __restrict__ beta, float* __restrict__ y)
{
    int n = blockIdx.x * 4 + (threadIdx.x >> 6);
    int lane = threadIdx.x & 63;
    int ch = lane * 4;
    float4 xv = *(const float4*)(x + (size_t)n * 256 + ch);
    float h0 = xv.x, h1 = xv.y, h2 = xv.z, h3 = xv.w;
    float den = denom[n * 8 + (lane >> 3)];
    float inv = (den > 0.f) ? 1.0f / den : 0.0f;
    const float* op = out + (size_t)n * 256 + ch;
    h0 += op[0] * inv; h1 += op[1] * inv;
    h2 += op[2] * inv; h3 += op[3] * inv;
    float s = h0 + h1 + h2 + h3;
#pragma unroll
    for (int off = 1; off < 64; off <<= 1) s += __shfl_xor(s, off);
    float mu = s * (1.0f / 256.0f);
    float d0 = h0 - mu, d1 = h1 - mu, d2 = h2 - mu, d3 = h3 - mu;
    float q = d0 * d0 + d1 * d1 + d2 * d2 + d3 * d3;
#pragma unroll
    for (int off = 1; off < 64; off <<= 1) q += __shfl_xor(q, off);
    float rstd = rsqrtf(q * (1.0f / 256.0f) + 1e-5f);
    float4 gv = *(const float4*)(gamma + ch);
    float4 bv = *(const float4*)(beta + ch);
    float4 o;
    o.x = d0 * rstd * gv.x + bv.x;
    o.y = d1 * rstd * gv.y + bv.y;
    o.z = d2 * rstd * gv.z + bv.z;
    o.w = d3 * rstd * gv.w + bv.w;
    *(float4*)(y + (size_t)n * 256 + ch) = o;
}

// ---------------------------------------------------------------------------
extern "C" void kernel_launch(void* const* d_in, const int* in_sizes, int n_in,
                              void* d_out, int out_size, void* d_ws, size_t ws_size,
                              hipStream_t stream)
{
    const float* x     = (const float*)d_in[0];
    const int*   src   = (const int*)d_in[1];
    const int*   dst   = (const int*)d_in[2];
    const float* Wq    = (const float*)d_in[3];
    const float* bq    = (const float*)d_in[4];
    const float* Wk    = (const float*)d_in[5];
    const float* bk    = (const float*)d_in[6];
    const float* Wv    = (const float*)d_in[7];
    const float* bv    = (const float*)d_in[8];
    const float* spd_w = (const float*)d_in[9];
    const float* gamma = (const float*)d_in[10];
    const float* beta  = (const float*)d_in[11];
    float* y = (float*)d_out;

    char* ws = (char*)d_ws;
    // denom+outf zeroed by prep_k zero-blocks (270336 B from ws+0).
    float* denom     = (float*)(ws + 0);          //   8192 B
    float* outf      = (float*)(ws + 8192);       // 262144 B -> 270336
    u32*   bin_off   = (u32*)(ws + 270336);       //  16388 B (pad) -> 286976
    unsigned char* T = (unsigned char*)(ws + 286976); // 65536 B -> 352512
    u32*   blockhist = (u32*)(ws + 352512);       // 64*4096*4 = 1 MB -> 1401088
    u32*   pinmask   = (u32*)(ws + 1401088);      // 64*2048*4 = 512 KB -> 1925376
    u32*   blockbase = (u32*)(ws + 1925376);      // 1 MB -> 2973952
    u32*   ssrc      = (u32*)(ws + 2973952);      // 1.2 MB -> 4202752
    u16*   Qb        = (u16*)(ws + 4202752);      // 128 KB -> 4333824
    u16*   Kb        = (u16*)(ws + 4333824);      // 25.6 MB -> 29933824
    u16*   Vb        = (u16*)(ws + 29933824);     // 25.6 MB -> 55533824
    u16*   Wb        = (u16*)(ws + 55533824);     // 384 KB (end ~55.9 MB)

    dim3 blk(256);
    prep_k<<<dim3(322), blk, 0, stream>>>(Wk, Wv, Wq, Wb, src, dst,
                                          blockhist, pinmask, (u32*)(ws + 0));
    gemm3<<<dim3(GOFF + NWG_GEMM + NWG_LN), blk, 0, stream>>>(
        x, Wb, bk, bv, bq, Kb, Vb, Qb, blockhist, bin_off, pinmask, T,
        gamma, beta, y);
    base_k<<<dim3(16), blk, 0, stream>>>(blockhist, bin_off, blockbase);
    scatter2_k<<<dim3(NB2), blk, 0, stream>>>(src, dst, blockbase, ssrc);
    agg_k<<<dim3(NBIN), blk, 0, stream>>>(ssrc, bin_off, Qb, Kb, Vb, T, spd_w, outf, denom);
    ln_k<<<dim3(64), blk, 0, stream>>>(x, outf, denom, gamma, beta, y);
}

// Round 12
// 197.160 us; speedup vs baseline: 1.3736x; 1.0181x over previous
//
#include <hip/hip_runtime.h>
#include <stdint.h>

#define N_NODES 50000
#define E_EDGES 300000
#define C_CH    256
#define H_HEADS 8
#define NB2     64       // blocks in counting sort
#define CHUNK2  4688     // edges per sort block (64*4688 >= 300000)
#define NBIN    4096     // 256 dst x 16 src-ranges
#define SRCDIV  3125     // 50000/16 -> src-range = s/3125
#define NWG_GEMM 1568    // 391*4 (K,V m-tiles) + 4 (Q)
#define NWG_LN   12436   // (50000-256)/4 ln-tail blocks
#define GOFF     66      // gemm blocks start here (0=scan, 1=SPD, 2..65=scatter)

typedef unsigned short u16;
typedef unsigned int   u32;

typedef __attribute__((ext_vector_type(8))) short  v8s;   // 8 bf16 (MFMA A/B frag)
typedef __attribute__((ext_vector_type(4))) float  v4f;   // MFMA C/D frag

__device__ __forceinline__ float bf2f(u16 v) {
    union { u32 u; float f; } x; x.u = ((u32)v) << 16; return x.f;
}
__device__ __forceinline__ u16 f2bf(float f) {
    union { float f; u32 u; } x; x.f = f;
    u32 r = (x.u + 0x7FFFu + ((x.u >> 16) & 1u)) >> 16;
    return (u16)r;
}
__device__ __forceinline__ void unp2(u32 v, float& lo, float& hi) {
    union { u32 u; float f; } x;
    x.u = v << 16; lo = x.f;
    x.u = v & 0xFFFF0000u; hi = x.f;
}
// async global->LDS, 16 B/lane; LDS dest = wave-uniform base + lane*16
__device__ __forceinline__ void gl_lds16(const u16* g, u16* l) {
    __builtin_amdgcn_global_load_lds(
        (const __attribute__((address_space(1))) void*)g,
        (__attribute__((address_space(3))) void*)l, 16, 0, 0);
}
// pack 8 fp32 -> 8 bf16, single 16B LDS store (round-4 exact)
__device__ __forceinline__ void pack8(const float4 p, const float4 q, u16* dst) {
    u16 tmp[8];
    tmp[0]=f2bf(p.x); tmp[1]=f2bf(p.y); tmp[2]=f2bf(p.z); tmp[3]=f2bf(p.w);
    tmp[4]=f2bf(q.x); tmp[5]=f2bf(q.y); tmp[6]=f2bf(q.z); tmp[7]=f2bf(q.w);
    *(uint4*)dst = *(const uint4*)tmp;
}

// ---------------------------------------------------------------------------
// prep_k: blocks 0..191 convert Wk,Wv,Wq -> bf16 Wb; blocks 192..255 run the
// (dst, src-range) histogram + per-block anchor masks (race-free: per-block
// output arrays); blocks 256..321 zero the denom+outf region.
// ---------------------------------------------------------------------------
__global__ __launch_bounds__(256) void prep_k(
    const float* __restrict__ Wk, const float* __restrict__ Wv,
    const float* __restrict__ Wq, u16* __restrict__ Wb,
    const int* __restrict__ src, const int* __restrict__ dst,
    u32* __restrict__ blockhist, u32* __restrict__ pinmask,
    u32* __restrict__ zero0)
{
    __shared__ u32 hist[NBIN];          // 16 KB
    __shared__ u32 mask[256][8];        //  8 KB
    int t = threadIdx.x, b = blockIdx.x;
    if (b < 192) {
        int m = (b < 64) ? 0 : (b < 128) ? 1 : 2;
        const float* sp = (m == 0) ? Wk : (m == 1) ? Wv : Wq;
        u16* dp = Wb + m * 65536;
        int i = (b & 63) * 1024 + t * 4;
        float4 v = *(const float4*)(sp + i);
        ushort4 o;
        o.x = f2bf(v.x); o.y = f2bf(v.y); o.z = f2bf(v.z); o.w = f2bf(v.w);
        *(ushort4*)(dp + i) = o;
        return;
    }
    if (b >= 256) {                      // zero blocks: 66 x 4096 B = 270336 B
        int z = b - 256;
        uint4 zv = make_uint4(0, 0, 0, 0);
        *(uint4*)(zero0 + z * 1024 + t * 4) = zv;
        return;
    }
    int hb = b - 192;                    // 0..63
#pragma unroll
    for (int j = 0; j < 16; j++) hist[t + j * 256] = 0;
#pragma unroll
    for (int w = 0; w < 8; w++) mask[t][w] = 0;
    __syncthreads();
    int start = hb * CHUNK2;
    int end = start + CHUNK2; if (end > E_EDGES) end = E_EDGES;
    for (int e = start + t; e < end; e += 256) {
        int d = dst[e], s = src[e];
        atomicAdd(&hist[d * 16 + s / SRCDIV], 1u);     // LDS atomic
        if (s < 256) atomicOr(&mask[d][s >> 5], 1u << (s & 31));
    }
    __syncthreads();
#pragma unroll
    for (int j = 0; j < 16; j++)
        blockhist[hb * NBIN + t + j * 256] = hist[t + j * 256];
#pragma unroll
    for (int w = 0; w < 8; w++)          // transposed: [hb][w][i], coalesced
        pinmask[hb * 2048 + w * 256 + t] = mask[t][w];
}

// ---------------------------------------------------------------------------
// Megakernel.  Block 0 = scan (bin_off for agg), block 1 = SPD, blocks
// 2..65 = SORT-SCATTER (each block INDEPENDENTLY recomputes bin totals +
// exclusive scan + its own per-block prefix from blockhist — no cross-block
// sync; ~8us each, all 64 in parallel, hidden under the gemm span; replaces
// the base_k + scatter2_k launches).  All helper reductions are b2-outer
// loop-interchanged (r9's j-outer form = 113us serial pole) and sit in the
// FIRST resident wave (r10's tail placement = 30us idle tail).  Blocks
// 66..1633: bf16 GEMM — EXACT round-4/8 inner code (r5/r6/r7 proved every
// core edit at the 64-VGPR cliff regresses).  Blocks 1634..: LayerNorm tail.
// ---------------------------------------------------------------------------
__global__ __launch_bounds__(256, 4) void gemm3(
    const float* __restrict__ x, const u16* __restrict__ Wb,
    const float* __restrict__ bk, const float* __restrict__ bv,
    const float* __restrict__ bq,
    u16* __restrict__ Kb, u16* __restrict__ Vb, u16* __restrict__ Qb,
    const u32* __restrict__ blockhist, u32* __restrict__ bin_off,
    const u32* __restrict__ pinmask, unsigned char* __restrict__ T,
    const int* __restrict__ src, const int* __restrict__ dst,
    u32* __restrict__ ssrc,
    const float* __restrict__ gamma, const float* __restrict__ beta,
    float* __restrict__ y)
{
    __shared__ u16 smem[4][128 * 32];   // 32 KB: A dbuf [0,1], B dbuf [2,3]
    __shared__ u32 ts[256];             //  1 KB scan temp (helpers only)
    const int t = threadIdx.x;

    if (blockIdx.x == 0) {
        // ---- scan: totals from blockhist (b2-outer, 16 parallel chains),
        //      exclusive scan -> bin_off (for agg_k) ----
        u32* tots = (u32*)&smem[0][0];            // 16 KB
        u32 c[16];
#pragma unroll
        for (int j = 0; j < 16; j++) c[j] = 0;
        for (int b2 = 0; b2 < NB2; b2++) {
#pragma unroll
            for (int j = 0; j < 16; j++)
                c[j] += blockhist[b2 * NBIN + j * 256 + t];
        }
#pragma unroll
        for (int j = 0; j < 16; j++) tots[j * 256 + t] = c[j];
        __syncthreads();
        u32 loc[16]; u32 a = 0;
#pragma unroll
        for (int j = 0; j < 16; j++) { loc[j] = tots[t * 16 + j]; a += loc[j]; }
        ts[t] = a;
        __syncthreads();
        for (int off = 1; off < 256; off <<= 1) {
            u32 add = (t >= off) ? ts[t - off] : 0u;
            __syncthreads();
            ts[t] += add;
            __syncthreads();
        }
        u32 base = ts[t] - a;
#pragma unroll
        for (int j = 0; j < 16; j++) { bin_off[t * 16 + j] = base; base += loc[j]; }
        if (t == 255) bin_off[NBIN] = base;
        return;
    }
    if (blockIdx.x == 1) {
        // ---- SPD: OR per-block masks (b2-outer, 8 parallel chains),
        //      3-level reachability -> T ----
        u32* b32 = (u32*)&smem[0][0];
        u32 (*F1)[8] = (u32(*)[8])(b32);
        u32 (*F2)[8] = (u32(*)[8])(b32 + 2048);
        u32 (*F3)[8] = (u32(*)[8])(b32 + 4096);
        int i = t;
        u32 mm[8];
#pragma unroll
        for (int w = 0; w < 8; w++) mm[w] = 0;
        for (int b2 = 0; b2 < NB2; b2++) {
#pragma unroll
            for (int w = 0; w < 8; w++)
                mm[w] |= pinmask[b2 * 2048 + w * 256 + i];
        }
#pragma unroll
        for (int w = 0; w < 8; w++) { F1[i][w] = mm[w]; F2[i][w] = 0; F3[i][w] = 0; }
        __syncthreads();
        for (int w = 0; w < 8; w++) {
            u32 m = F1[i][w];
            while (m) {
                int b = __ffs(m) - 1; m &= m - 1;
                int s = w * 32 + b;
#pragma unroll
                for (int j = 0; j < 8; j++) F2[i][j] |= F1[s][j];
            }
        }
        __syncthreads();
        for (int w = 0; w < 8; w++) {
            u32 m = F1[i][w];
            while (m) {
                int b = __ffs(m) - 1; m &= m - 1;
                int s = w * 32 + b;
#pragma unroll
                for (int j = 0; j < 8; j++) F3[i][j] |= F2[s][j];
            }
        }
        __syncthreads();
        for (int w = 0; w < 8; w++) {
            u32 f1 = F1[i][w], f2 = F2[i][w], f3 = F3[i][w];
#pragma unroll
            for (int g = 0; g < 8; g++) {
                u32 word = 0;
#pragma unroll
                for (int b = 0; b < 4; b++) {
                    int bit = g * 4 + b;
                    u32 k = ((f1 >> bit) & 1u) ? 1u : ((f2 >> bit) & 1u) ? 2u
                           : ((f3 >> bit) & 1u) ? 3u : 4u;
                    word |= k << (8 * b);
                }
                *(u32*)(T + i * 256 + w * 32 + g * 4) = word;
            }
        }
        return;
    }
    if (blockIdx.x < GOFF) {
        // ---- sort-scatter block b (0..63): independent scan + own prefix,
        //      then scatter src values into (dst, src-range) buckets ----
        int b = blockIdx.x - 2;
        u32* tots = (u32*)&smem[0][0];            // [0, 16K)
        u32* pre  = tots + NBIN;                  // [16K, 32K)
        u32 ctot[16], cpre[16];
#pragma unroll
        for (int j = 0; j < 16; j++) { ctot[j] = 0; cpre[j] = 0; }
        for (int b2 = 0; b2 < NB2; b2++) {        // b2-outer: 16 parallel chains
#pragma unroll
            for (int j = 0; j < 16; j++) {
                u32 h = blockhist[b2 * NBIN + j * 256 + t];
                ctot[j] += h;
                if (b2 < b) cpre[j] += h;
            }
        }
#pragma unroll
        for (int j = 0; j < 16; j++) {
            tots[j * 256 + t] = ctot[j];
            pre[j * 256 + t]  = cpre[j];
        }
        __syncthreads();
        u32 loc[16], prer[16]; u32 a = 0;
#pragma unroll
        for (int j = 0; j < 16; j++) {
            loc[j] = tots[t * 16 + j];
            prer[j] = pre[t * 16 + j];
            a += loc[j];
        }
        ts[t] = a;
        __syncthreads();
        for (int off = 1; off < 256; off <<= 1) {
            u32 add = (t >= off) ? ts[t - off] : 0u;
            __syncthreads();
            ts[t] += add;
            __syncthreads();
        }
        u32 run = ts[t] - a;
        u32* cur = tots;                          // alias; tots reads all done
#pragma unroll
        for (int j = 0; j < 16; j++) {
            cur[t * 16 + j] = run + prer[j];      // global base + own prefix
            run += loc[j];
        }
        __syncthreads();
        int start = b * CHUNK2;
        int end = start + CHUNK2; if (end > E_EDGES) end = E_EDGES;
        for (int e = start + t; e < end; e += 256) {
            int s = src[e];
            int bin = dst[e] * 16 + s / SRCDIV;
            u32 pos = atomicAdd(&cur[bin], 1u);   // LDS atomic
            ssrc[pos] = (u32)s;
        }
        return;
    }
    if (blockIdx.x >= GOFF + NWG_GEMM) {
        // ---- LayerNorm tail: nodes 256..49999 (no agg contribution) ----
        int n = (blockIdx.x - (GOFF + NWG_GEMM)) * 4 + (t >> 6) + 256;
        int lane = t & 63;
        int ch = lane * 4;
        float4 xv = *(const float4*)(x + (size_t)n * 256 + ch);
        float h0 = xv.x, h1 = xv.y, h2 = xv.z, h3 = xv.w;
        float s = h0 + h1 + h2 + h3;
#pragma unroll
        for (int off = 1; off < 64; off <<= 1) s += __shfl_xor(s, off);
        float mu = s * (1.0f / 256.0f);
        float d0 = h0 - mu, d1 = h1 - mu, d2 = h2 - mu, d3 = h3 - mu;
        float qq = d0 * d0 + d1 * d1 + d2 * d2 + d3 * d3;
#pragma unroll
        for (int off = 1; off < 64; off <<= 1) qq += __shfl_xor(qq, off);
        float rstd = rsqrtf(qq * (1.0f / 256.0f) + 1e-5f);
        float4 gv = *(const float4*)(gamma + ch);
        float4 bv = *(const float4*)(beta + ch);
        float4 o;
        o.x = d0 * rstd * gv.x + bv.x;
        o.y = d1 * rstd * gv.y + bv.y;
        o.z = d2 * rstd * gv.z + bv.z;
        o.w = d3 * rstd * gv.w + bv.w;
        *(float4*)(y + (size_t)n * 256 + ch) = o;
        return;
    }

    // ---- GEMM (round-4 exact inner code; compact grid) ----
    // bijective XCD-chunked swizzle (nwg=1568 % 8 == 0), m-tile-major: the
    // 4 (mat,nh) K/V blocks of an m-tile share one XCD L2.
    int gid = blockIdx.x - GOFF;
    int xcd = gid & 7, pos = gid >> 3;
    int wgid = xcd * (NWG_GEMM >> 3) + pos;      // 196 per XCD
    int mt, mat, nh;
    if (wgid < 1564) { mt = wgid >> 2; int j = wgid & 3; mat = j >> 1; nh = j & 1; }
    else             { int qi = wgid - 1564; mt = qi >> 1; mat = 2; nh = qi & 1; }
    const int m0 = mt * 128;
    const int M = (mat == 2) ? 256 : N_NODES;
    const u16* W = Wb + mat * 65536;
    const float* bias = (mat == 0) ? bk : (mat == 1) ? bv : bq;
    u16* OUT = (mat == 0) ? Kb : (mat == 1) ? Vb : Qb;
    const int n0 = nh * 128;

    const int lane = t & 63, w = t >> 6;
    const int quad = lane >> 4, l15 = lane & 15;
    const int mq = w & 1, nq = w >> 1;

    v4f acc[16];
#pragma unroll
    for (int i = 0; i < 16; i++) acc[i] = (v4f)(0.0f);

    const int lrow = lane >> 2;               // 0..15
    const int cg   = (lane & 3) * 8;          // fp32 col-group offset
    int rA0 = m0 + w * 32 + lrow; if (rA0 > 49999) rA0 = 49999;
    int rA1 = rA0 + 16;           if (rA1 > 49999) rA1 = 49999;
    const float* gA0 = x + (size_t)rA0 * 256 + cg;
    const float* gA1 = x + (size_t)rA1 * 256 + cg;
    const u16* gB = W + (size_t)(n0 + w * 32 + lrow) * 256 + (lane & 3) * 8;

    u16* ldsA = &smem[0][(w * 32 + lrow) * 32 + (lane & 3) * 8];

    float4 a00, a01, a10, a11;
#define LOADA(kt) do {                                   \
    a00 = *(const float4*)(gA0 + (kt) * 32);             \
    a01 = *(const float4*)(gA0 + (kt) * 32 + 4);         \
    a10 = *(const float4*)(gA1 + (kt) * 32);             \
    a11 = *(const float4*)(gA1 + (kt) * 32 + 4);         \
} while (0)
#define WRITEA(bi) do {                                  \
    pack8(a00, a01, ldsA + (bi) * 4096);                 \
    pack8(a10, a11, ldsA + (bi) * 4096 + 16 * 32);       \
} while (0)
#define STAGEB(bi, koff) do {                                             \
    gl_lds16(gB + (koff),            &smem[2 + (bi)][(w * 32) * 32]);     \
    gl_lds16(gB + 16 * 256 + (koff), &smem[2 + (bi)][(w * 32 + 16) * 32]);\
} while (0)

    LOADA(0);
    STAGEB(0, 0);
    WRITEA(0);
    __syncthreads();                          // drain prologue (vm + lgkm)
    for (int kt = 0; kt < 8; kt++) {
        const int cur = kt & 1;
        if (kt < 7) { LOADA(kt + 1); STAGEB(cur ^ 1, (kt + 1) * 32); }
        v8s a[4], b[4];
#pragma unroll
        for (int f = 0; f < 4; f++)
            a[f] = *(const v8s*)(&smem[cur][(mq * 64 + f * 16 + l15) * 32 + quad * 8]);
#pragma unroll
        for (int f = 0; f < 4; f++)
            b[f] = *(const v8s*)(&smem[2 + cur][(nq * 64 + f * 16 + l15) * 32 + quad * 8]);
#pragma unroll
        for (int fm = 0; fm < 4; fm++)
#pragma unroll
            for (int fn = 0; fn < 4; fn++)
                acc[fm * 4 + fn] = __builtin_amdgcn_mfma_f32_16x16x32_bf16(
                    a[fm], b[fn], acc[fm * 4 + fn], 0, 0, 0);
        if (kt < 7) WRITEA(cur ^ 1);          // fp32 loads landed under MFMA
        __syncthreads();                      // drains vm (B) + lgkm (A writes)
    }
#undef LOADA
#undef WRITEA
#undef STAGEB

    // Epilogue: stage C+bias into LDS (32 KB = all 4 buffers), coalesced
    // uint4 stores (full 64 B lines -> no write amplification).
    u16* S = &smem[0][0];
#pragma unroll
    for (int fn = 0; fn < 4; fn++) {
        int n = nq * 64 + fn * 16 + l15;
        float bi = bias[n0 + n];
#pragma unroll
        for (int fm = 0; fm < 4; fm++) {
#pragma unroll
            for (int r2 = 0; r2 < 4; r2++) {
                int row = mq * 64 + fm * 16 + quad * 4 + r2;
                S[row * 128 + n] = f2bf(acc[fm * 4 + fn][r2] + bi);
            }
        }
    }
    __syncthreads();
#pragma unroll
    for (int i = 0; i < 8; i++) {
        int c = i * 256 + t;
        int row = c >> 4;
        int m = m0 + row;
        if (m < M)
            *(uint4*)(OUT + (size_t)m * 256 + n0 + (c & 15) * 8) =
                *(const uint4*)(S + c * 8);
    }
}

// ---------------------------------------------------------------------------
// Fused scores+aggregate.  blockIdx = d*16 + src-range p -> each block's K/V
// gather stays inside a 3.2 MB src window; blockIdx%8 == p%8 pins a window
// pair per XCD L2.  2-deep pipeline: src 2 iters ahead, K/V rows 1 ahead.
// ---------------------------------------------------------------------------
__global__ __launch_bounds__(256) void agg_k(
    const u32* __restrict__ ssrc, const u32* __restrict__ bin_off,
    const u16* __restrict__ Qb, const u16* __restrict__ Kb,
    const u16* __restrict__ Vb, const unsigned char* __restrict__ T,
    const float* __restrict__ spd_w, float* __restrict__ out,
    float* __restrict__ denom)
{
    __shared__ float red[4 * 256];
    __shared__ float dred[4 * 8];
    int bid = blockIdx.x;
    int d = bid >> 4;
    int t = threadIdx.x, lane = t & 63, wave = t >> 6;
    int half = lane >> 5, sl = lane & 31;
    int h = sl >> 2;                        // head = (sl*8)>>5
    u32 start = bin_off[bid], end = bin_off[bid + 1];

    uint4 qv = *(const uint4*)(Qb + (size_t)d * 256 + sl * 8);
    float q0,q1,q2,q3,q4,q5,q6,q7;
    unp2(qv.x,q0,q1); unp2(qv.y,q2,q3); unp2(qv.z,q4,q5); unp2(qv.w,q6,q7);
    float sw4 = spd_w[4 * 8 + h];           // spd=4 bias (src>=256, ~98.5%)

    float a0=0.f,a1=0.f,a2=0.f,a3=0.f,a4=0.f,a5=0.f,a6=0.f,a7=0.f,dsum=0.f;

    u32 i = start + (u32)(wave * 2 + half);  // 8 slots, stride 8
    int s_c = 0, s_n = 0;
    uint4 kv_c = make_uint4(0,0,0,0), vv_c = kv_c;
    if (i < end) {
        s_c = (int)ssrc[i];
        kv_c = *(const uint4*)(Kb + (size_t)s_c * 256 + sl * 8);
        vv_c = *(const uint4*)(Vb + (size_t)s_c * 256 + sl * 8);
        if (i + 8 < end) s_n = (int)ssrc[i + 8];
    }
    while (i < end) {
        u32 inx = i + 8;
        uint4 kv_n = kv_c, vv_n = vv_c;
        if (inx < end) {                    // issue next row loads (addr ready)
            kv_n = *(const uint4*)(Kb + (size_t)s_n * 256 + sl * 8);
            vv_n = *(const uint4*)(Vb + (size_t)s_n * 256 + sl * 8);
        }
        int s_nn = (inx + 8 < end) ? (int)ssrc[inx + 8] : 0;
        float k0,k1,k2,k3,k4,k5,k6,k7, v0,v1,v2,v3,v4,v5,v6,v7;
        unp2(kv_c.x,k0,k1); unp2(kv_c.y,k2,k3); unp2(kv_c.z,k4,k5); unp2(kv_c.w,k6,k7);
        unp2(vv_c.x,v0,v1); unp2(vv_c.y,v2,v3); unp2(vv_c.z,v4,v5); unp2(vv_c.w,v6,v7);
        float p = q0*k0+q1*k1+q2*k2+q3*k3+q4*k4+q5*k5+q6*k6+q7*k7;
        p += __shfl_xor(p, 1);
        p += __shfl_xor(p, 2);              // head dot over 4 lanes x 8 ch
        float bias = (s_c < 256) ? spd_w[(int)T[s_c * 256 + d] * 8 + h] : sw4;
        float wgt = __expf(p * 0.17677669529663689f + bias);
        a0 += wgt*v0; a1 += wgt*v1; a2 += wgt*v2; a3 += wgt*v3;
        a4 += wgt*v4; a5 += wgt*v5; a6 += wgt*v6; a7 += wgt*v7;
        if ((sl & 3) == 0) dsum += wgt;
        i = inx; s_c = s_n; s_n = s_nn; kv_c = kv_n; vv_c = vv_n;
    }
    a0 += __shfl_xor(a0,32); a1 += __shfl_xor(a1,32);
    a2 += __shfl_xor(a2,32); a3 += __shfl_xor(a3,32);
    a4 += __shfl_xor(a4,32); a5 += __shfl_xor(a5,32);
    a6 += __shfl_xor(a6,32); a7 += __shfl_xor(a7,32);
    dsum += __shfl_xor(dsum,32);
    if (half == 0) {
        *(float4*)(&red[wave * 256 + sl * 8])     = make_float4(a0,a1,a2,a3);
        *(float4*)(&red[wave * 256 + sl * 8 + 4]) = make_float4(a4,a5,a6,a7);
        if ((sl & 3) == 0) dred[wave * 8 + h] = dsum;
    }
    __syncthreads();
    float sAll = red[t] + red[256 + t] + red[512 + t] + red[768 + t];
    atomicAdd(&out[(size_t)d * 256 + t], sAll);
    if (t < 8) {
        float ds = dred[t] + dred[8 + t] + dred[16 + t] + dred[24 + t];
        atomicAdd(&denom[d * 8 + t], ds);
    }
}

// ---------------------------------------------------------------------------
// LayerNorm anchors (n < 256 only): h = out/denom + x.  Tail nodes were
// normalized inside the megakernel.  64 blocks.
// ---------------------------------------------------------------------------
__global__ __launch_bounds__(256) void ln_k(
    const float* __restrict__ x, const float* __restrict__ out,
    const float* __restrict__ denom, const float* __restrict__ gamma,
    const float* __restrict__ beta, float* __restrict__ y)
{
    int n = blockIdx.x * 4 + (threadIdx.x >> 6);
    int lane = threadIdx.x & 63;
    int ch = lane * 4;
    float4 xv = *(const float4*)(x + (size_t)n * 256 + ch);
    float h0 = xv.x, h1 = xv.y, h2 = xv.z, h3 = xv.w;
    float den = denom[n * 8 + (lane >> 3)];
    float inv = (den > 0.f) ? 1.0f / den : 0.0f;
    const float* op = out + (size_t)n * 256 + ch;
    h0 += op[0] * inv; h1 += op[1] * inv;
    h2 += op[2] * inv; h3 += op[3] * inv;
    float s = h0 + h1 + h2 + h3;
#pragma unroll
    for (int off = 1; off < 64; off <<= 1) s += __shfl_xor(s, off);
    float mu = s * (1.0f / 256.0f);
    float d0 = h0 - mu, d1 = h1 - mu, d2 = h2 - mu, d3 = h3 - mu;
    float q = d0 * d0 + d1 * d1 + d2 * d2 + d3 * d3;
#pragma unroll
    for (int off = 1; off < 64; off <<= 1) q += __shfl_xor(q, off);
    float rstd = rsqrtf(q * (1.0f / 256.0f) + 1e-5f);
    float4 gv = *(const float4*)(gamma + ch);
    float4 bv = *(const float4*)(beta + ch);
    float4 o;
    o.x = d0 * rstd * gv.x + bv.x;
    o.y = d1 * rstd * gv.y + bv.y;
    o.z = d2 * rstd * gv.z + bv.z;
    o.w = d3 * rstd * gv.w + bv.w;
    *(float4*)(y + (size_t)n * 256 + ch) = o;
}

// ---------------------------------------------------------------------------
extern "C" void kernel_launch(void* const* d_in, const int* in_sizes, int n_in,
                              void* d_out, int out_size, void* d_ws, size_t ws_size,
                              hipStream_t stream)
{
    const float* x     = (const float*)d_in[0];
    const int*   src   = (const int*)d_in[1];
    const int*   dst   = (const int*)d_in[2];
    const float* Wq    = (const float*)d_in[3];
    const float* bq    = (const float*)d_in[4];
    const float* Wk    = (const float*)d_in[5];
    const float* bk    = (const float*)d_in[6];
    const float* Wv    = (const float*)d_in[7];
    const float* bv    = (const float*)d_in[8];
    const float* spd_w = (const float*)d_in[9];
    const float* gamma = (const float*)d_in[10];
    const float* beta  = (const float*)d_in[11];
    float* y = (float*)d_out;

    char* ws = (char*)d_ws;
    // denom+outf zeroed by prep_k zero-blocks (270336 B from ws+0).
    float* denom     = (float*)(ws + 0);          //   8192 B
    float* outf      = (float*)(ws + 8192);       // 262144 B -> 270336
    u32*   bin_off   = (u32*)(ws + 270336);       //  16388 B (pad) -> 286976
    unsigned char* T = (unsigned char*)(ws + 286976); // 65536 B -> 352512
    u32*   blockhist = (u32*)(ws + 352512);       // 64*4096*4 = 1 MB -> 1401088
    u32*   pinmask   = (u32*)(ws + 1401088);      // 64*2048*4 = 512 KB -> 1925376
    u32*   ssrc      = (u32*)(ws + 1925376);      // 1.2 MB -> 3125376
    u16*   Qb        = (u16*)(ws + 3125376);      // 128 KB -> 3256448
    u16*   Kb        = (u16*)(ws + 3256448);      // 25.6 MB -> 28881024
    u16*   Vb        = (u16*)(ws + 28881024);     // 25.6 MB -> 54505600
    u16*   Wb        = (u16*)(ws + 54505600);     // 384 KB (end ~54.9 MB)

    dim3 blk(256);
    prep_k<<<dim3(322), blk, 0, stream>>>(Wk, Wv, Wq, Wb, src, dst,
                                          blockhist, pinmask, (u32*)(ws + 0));
    gemm3<<<dim3(GOFF + NWG_GEMM + NWG_LN), blk, 0, stream>>>(
        x, Wb, bk, bv, bq, Kb, Vb, Qb, blockhist, bin_off, pinmask, T,
        src, dst, ssrc, gamma, beta, y);
    agg_k<<<dim3(NBIN), blk, 0, stream>>>(ssrc, bin_off, Qb, Kb, Vb, T, spd_w, outf, denom);
    ln_k<<<dim3(64), blk, 0, stream>>>(x, outf, denom, gamma, beta, y);
}